// Round 4
// baseline (1232.842 us; speedup 1.0000x reference)
//
#include <hip/hip_runtime.h>
#include <hip/hip_bf16.h>

typedef __hip_bfloat16 bf16;

#define DEVI __device__ __forceinline__

DEVI float cvt(float x){ return x; }
DEVI float cvt(bf16 x){ return __bfloat162float(x); }

DEVI void stg(float* p, float v){ *p = v; }
DEVI void stg(bf16* p, float v){ *p = __float2bfloat16(v); }

DEVI float gelu_exact(float x){
  return 0.5f*x*(1.0f + erff(x*0.70710678118654752440f));
}

// problem constants
constexpr int B_ = 2, C_ = 128, H_ = 56, W_ = 56, N_ = 3136, NH_ = 4, D_ = 32, HF_ = 341;
constexpr int ROWS_ = B_*N_;             // 6272

// ---------------- LayerNorm (one wave per row of 128 channels) ----------------
template<typename TX, typename TY, bool PLANES>
__global__ __launch_bounds__(256)
void ln_kernel(const TX* __restrict__ x, const float* __restrict__ w,
               const float* __restrict__ bia, TY* __restrict__ y)
{
  int gid = blockIdx.x*4 + (threadIdx.x>>6);      // row over B*N
  int lane = threadIdx.x & 63;
  int b = gid / N_, n = gid % N_;
  float v0, v1;
  if (PLANES){
    v0 = cvt(x[((long)b*C_ + lane     )*N_ + n]);
    v1 = cvt(x[((long)b*C_ + lane + 64)*N_ + n]);
  } else {
    v0 = cvt(x[(long)gid*C_ + lane     ]);
    v1 = cvt(x[(long)gid*C_ + lane + 64]);
  }
  float s = v0+v1, ss = v0*v0 + v1*v1;
  #pragma unroll
  for (int o=32;o>0;o>>=1){ s += __shfl_xor(s,o); ss += __shfl_xor(ss,o); }
  float mu  = s*(1.0f/128.0f);
  float var = fmaxf(ss*(1.0f/128.0f) - mu*mu, 0.f);
  float inv = rsqrtf(var + 1e-5f);
  stg(&y[(long)gid*C_ + lane     ], (v0-mu)*inv*w[lane     ] + bia[lane     ]);
  stg(&y[(long)gid*C_ + lane + 64], (v1-mu)*inv*w[lane + 64] + bia[lane + 64]);
}

// ---------------- generic tiled GEMM ----------------
// out[m,n] = sum_k A[m,k] * (TRANSB ? B[n,k] : B[k,n])  (all row-major)
// mode: 1 = +bias[col], 2 = +bias[col]+gelu, 3 = +bias[row],
//       4 = +bias[col]+res[flat], 5 = +bias[row]+res[flat]
template<typename TA, typename TB, bool TRANSB, typename TC, typename TR>
__global__ __launch_bounds__(256)
void gemm_kernel(const TA* __restrict__ A, const TB* __restrict__ Bm,
                 const float* __restrict__ bias, const TR* __restrict__ res,
                 TC* __restrict__ Cm, int M, int Nn, int Kk, int mode)
{
  __shared__ float As[16][64];
  __shared__ float Bs[16][64];
  int tid = threadIdx.x;
  int tx = tid & 15, ty = tid >> 4;
  int m0 = blockIdx.y*64, n0 = blockIdx.x*64;
  float acc[4][4] = {};
  for (int k0 = 0; k0 < Kk; k0 += 16){
    #pragma unroll
    for (int i=0;i<4;i++){
      int idx = tid*4 + i;
      int mm = idx >> 4, kk = idx & 15;
      int gm = m0+mm, gk = k0+kk;
      As[kk][mm] = (gm<M && gk<Kk) ? cvt(A[(long)gm*Kk + gk]) : 0.f;
    }
    #pragma unroll
    for (int i=0;i<4;i++){
      if (TRANSB){
        int idx = tid*4 + i;
        int nn = idx >> 4, kk = idx & 15;
        int gn = n0+nn, gk = k0+kk;
        Bs[kk][nn] = (gn<Nn && gk<Kk) ? cvt(Bm[(long)gn*Kk + gk]) : 0.f;
      } else {
        int idx = tid + i*256;
        int kk = idx >> 6, nn = idx & 63;
        int gn = n0+nn, gk = k0+kk;
        Bs[kk][nn] = (gn<Nn && gk<Kk) ? cvt(Bm[(long)gk*Nn + gn]) : 0.f;
      }
    }
    __syncthreads();
    #pragma unroll
    for (int kk=0;kk<16;kk++){
      float a4[4], b4[4];
      #pragma unroll
      for (int i=0;i<4;i++) a4[i] = As[kk][ty*4+i];
      #pragma unroll
      for (int j=0;j<4;j++) b4[j] = Bs[kk][tx*4+j];
      #pragma unroll
      for (int i=0;i<4;i++)
        #pragma unroll
        for (int j=0;j<4;j++) acc[i][j] = fmaf(a4[i], b4[j], acc[i][j]);
    }
    __syncthreads();
  }
  #pragma unroll
  for (int i=0;i<4;i++){
    int gm = m0 + ty*4 + i;
    if (gm >= M) continue;
    #pragma unroll
    for (int j=0;j<4;j++){
      int gn = n0 + tx*4 + j;
      if (gn >= Nn) continue;
      float v = acc[i][j];
      if (mode==1 || mode==2 || mode==4) v += bias[gn];
      else                               v += bias[gm];
      if (mode==2) v = gelu_exact(v);
      if (mode==4 || mode==5) v += cvt(res[(long)gm*Nn + gn]);
      stg(&Cm[(long)gm*Nn + gn], v);
    }
  }
}

// ---------------- q post-process: l2n + embed + temperature -> qs planes ----------------
__global__ __launch_bounds__(256)
void post_q_kernel(const bf16* __restrict__ q_raw, const float* __restrict__ qe,
                   const float* __restrict__ temp, bf16* __restrict__ qs)
{
  int t = blockIdx.x*256 + threadIdx.x;        // (b*4+h)*N + n
  int n = t % N_; int bh = t / N_; int h = bh & 3; int b = bh >> 2;
  float sp = log1pf(expf(temp[h]));
  const bf16* qr = q_raw + ((long)(b*N_ + n))*C_ + h*D_;
  float v[32]; float ss = 0.f;
  #pragma unroll
  for (int d=0;d<32;d++){ v[d] = cvt(qr[d]); ss = fmaf(v[d], v[d], ss); }
  float inv = 1.f/fmaxf(sqrtf(ss), 1e-12f);
  #pragma unroll
  for (int d=0;d<32;d++)
    stg(&qs[((long)bh*D_ + d)*N_ + n], (v[d]*inv + qe[h*D_+d])*sp);
}

// ---------------- fused pool attention + local 3x3 + learnable tokens ----------------
// grid (49, 8); block 256 = 4 waves. Each block owns 64 queries (one per lane; all
// 4 waves hold the same q). Waves split the 98 key-tiles 4-way into wave-private LDS,
// normalize pool keys inline; block-level merge; wave 0 adds local part + writes xo.
// Exponent shift -8 applied to ALL exponentials (softmax-invariant, exact).
__global__ __launch_bounds__(256)
void attn_fused_kernel(const bf16* __restrict__ qs_, const bf16* __restrict__ kvp_,
                       const bf16* __restrict__ kv_,
                       const float* __restrict__ qe, const float* __restrict__ temp,
                       const float* __restrict__ tokens, const float* __restrict__ tbias,
                       float* __restrict__ xo)
{
  int bh = blockIdx.y; int h = bh & 3; int b = bh >> 2;
  int lane = threadIdx.x & 63;
  int w    = threadIdx.x >> 6;
  int n = blockIdx.x*64 + lane;                  // 49*64 = 3136 exact
  const bf16* qsp = qs_ + (long)bh*D_*N_;
  float q[32];
  #pragma unroll
  for (int d=0;d<32;d++) q[d] = cvt(qsp[(long)d*N_ + n]);
  __shared__ float sm[4][2144];                  // per wave: K 32x33 | V 32x33 | invnorm 32
  float* Ks = sm[w];
  float* Vs = Ks + 1056;
  float* Ns = Ks + 2112;
  const bf16* kvpb = kvp_ + (long)b*N_*(2*C_) + h*D_;   // rows (N, 256), head offset
  int lo = (w<2) ? w*25 : 50 + (w-2)*24;         // 25/25/24/24 of 98 tiles
  int hi = (w<2) ? lo+25 : lo+24;
  float l = 0.f, acc[32];
  #pragma unroll
  for (int d=0;d<32;d++) acc[d]=0.f;
  for (int tile=lo; tile<hi; tile++){            // wave-private: no block barrier needed
    int t0 = tile*32;
    #pragma unroll
    for (int i=0;i<16;i++){
      int idx = lane + i*64;
      int mm = idx >> 5, dd = idx & 31;
      Ks[mm*33+dd] = cvt(kvpb[(long)(t0+mm)*(2*C_) + dd]);
      Vs[mm*33+dd] = cvt(kvpb[(long)(t0+mm)*(2*C_) + C_ + dd]);
    }
    if (lane < 32){                              // inline l2-norm of the 32 pool keys
      float ss = 0.f;
      #pragma unroll
      for (int d=0;d<32;d++){ float kk = Ks[lane*33+d]; ss = fmaf(kk,kk,ss); }
      Ns[lane] = 1.f/fmaxf(sqrtf(ss), 1e-12f);
    }
    #pragma unroll 4
    for (int mm=0;mm<32;mm++){
      float s = 0.f;
      #pragma unroll
      for (int d=0;d<32;d++) s = fmaf(q[d], Ks[mm*33+d], s);
      float e = __expf(s*Ns[mm] - 8.f);
      l += e;
      #pragma unroll
      for (int d=0;d<32;d++) acc[d] = fmaf(e, Vs[mm*33+d], acc[d]);
    }
  }
  // block merge of 4 wave-partials (reuse sm; each wave writes only its region)
  __syncthreads();
  {
    float* red = sm[w];                          // [lane]=l, [(1+d)*64+lane]=acc[d]
    red[lane] = l;
    #pragma unroll
    for (int d=0;d<32;d++) red[(1+d)*64 + lane] = acc[d];
  }
  __syncthreads();
  if (threadIdx.x < 64){
    float L = 0.f, out[32];
    #pragma unroll
    for (int d=0;d<32;d++) out[d]=0.f;
    #pragma unroll
    for (int ww=0;ww<4;ww++){
      L += sm[ww][lane];
      #pragma unroll
      for (int d=0;d<32;d++) out[d] += sm[ww][(1+d)*64 + lane];
    }
    // local 3x3: keys/values straight from kv_raw rows, keys normalized inline.
    // Zero-padded (OOB) keys score exactly 0 (they stay in the softmax denominator).
    int hy = n / W_, wx = n % W_;
    const bf16* kvb = kv_ + (long)b*N_*(2*C_) + h*D_;
    float sl[9];
    #pragma unroll
    for (int k=0;k<9;k++){
      int di = k/3-1, dj = k%3-1;
      int yy = hy+di, xx = wx+dj;
      float s = 0.f;
      if (yy>=0 && yy<H_ && xx>=0 && xx<W_){
        long nn2 = (long)(yy*W_+xx)*(2*C_);
        float dot = 0.f, ss = 0.f;
        #pragma unroll
        for (int d=0;d<32;d++){
          float kk = cvt(kvb[nn2 + d]);
          dot = fmaf(q[d], kk, dot);
          ss  = fmaf(kk, kk, ss);
        }
        s = dot / fmaxf(sqrtf(ss), 1e-12f);
      }
      sl[k] = s;
    }
    #pragma unroll
    for (int k=0;k<9;k++) L += __expf(sl[k] - 8.f);
    float invL = 1.f/L;
    #pragma unroll
    for (int d=0;d<32;d++) out[d] *= invL;
    // qn = qs/softplus(temp) - qe
    float sp = log1pf(expf(temp[h]));
    float invsp = 1.f/sp;
    float qn[32];
    #pragma unroll
    for (int d=0;d<32;d++) qn[d] = q[d]*invsp - qe[h*D_+d];
    #pragma unroll
    for (int k=0;k<9;k++){
      float tok = 0.f;
      #pragma unroll
      for (int d=0;d<32;d++) tok = fmaf(qn[d], tokens[(h*D_+d)*9+k], tok);
      float wl = tok + tbias[h*9+k] + __expf(sl[k] - 8.f)*invL;
      int di = k/3-1, dj = k%3-1;
      int yy = hy+di, xx = wx+dj;
      if (yy>=0 && yy<H_ && xx>=0 && xx<W_){     // OOB v_l is zero-padded -> contributes 0
        long nn2 = (long)(yy*W_+xx)*(2*C_);
        #pragma unroll
        for (int d=0;d<32;d++) out[d] = fmaf(wl, cvt(kvb[nn2 + C_ + d]), out[d]);
      }
    }
    float* op = xo + ((long)(b*N_ + n))*C_ + h*D_;   // (B,N,C) rows
    #pragma unroll
    for (int d=0;d<32;d++) op[d] = out[d];
  }
}

// ---------------- depthwise 3x3 conv + bias + gelu, gate IN-PLACE over v ----------------
// one batch; f1 = planes (2*HF, N) bf16. g[c,n] = gelu(dw(a)[c,n]+b[c]) * f1[HF+c,n],
// written over f1[HF+c,n] (each element read only by its own thread -> race-free).
__global__ __launch_bounds__(256)
void dwconv_kernel(bf16* __restrict__ f1, const float* __restrict__ dww,
                   const float* __restrict__ dwb)
{
  int t = blockIdx.x*256 + threadIdx.x;
  if (t >= HF_*N_) return;
  int n = t % N_; int c = t / N_;
  int hy = n / W_, wx = n % W_;
  const bf16* ap = f1 + (long)c*N_;
  float s = dwb[c];
  #pragma unroll
  for (int di=-1; di<=1; di++)
    #pragma unroll
    for (int dj=-1; dj<=1; dj++){
      int yy = hy+di, xx = wx+dj;
      if (yy>=0 && yy<H_ && xx>=0 && xx<W_)
        s = fmaf(dww[c*9 + (di+1)*3 + (dj+1)], cvt(ap[yy*W_+xx]), s);
    }
  float ge = gelu_exact(s);
  long vi = ((long)(HF_+c))*N_ + n;
  stg(&f1[vi], ge*cvt(f1[vi]));
}

// ---------------- launcher ----------------
extern "C" void kernel_launch(void* const* d_in, const int* in_sizes, int n_in,
                              void* d_out, int out_size, void* d_ws, size_t ws_size,
                              hipStream_t stream)
{
  (void)in_sizes; (void)n_in; (void)out_size; (void)ws_size;
  // Reference setup_inputs() is jnp.float32 for every tensor -> fp32 pointers.
  const float* x_in      = (const float*)d_in[0];
  const float* norm1_w   = (const float*)d_in[1];
  const float* norm1_b   = (const float*)d_in[2];
  const float* q_w       = (const float*)d_in[3];
  const float* q_b       = (const float*)d_in[4];
  const float* kv_w      = (const float*)d_in[5];
  const float* kv_b      = (const float*)d_in[6];
  const float* temp      = (const float*)d_in[7];
  const float* qe        = (const float*)d_in[8];
  const float* tokens    = (const float*)d_in[9];
  const float* tbias     = (const float*)d_in[10];
  const float* sr_w      = (const float*)d_in[11];
  const float* sr_b      = (const float*)d_in[12];
  const float* pln_w     = (const float*)d_in[13];
  const float* pln_b     = (const float*)d_in[14];
  const float* proj_w    = (const float*)d_in[15];
  const float* proj_b    = (const float*)d_in[16];
  const float* norm2_w   = (const float*)d_in[17];
  const float* norm2_b   = (const float*)d_in[18];
  const float* fc1_w     = (const float*)d_in[19];
  const float* fc1_b     = (const float*)d_in[20];
  const float* dw_w      = (const float*)d_in[21];
  const float* dw_b      = (const float*)d_in[22];
  const float* fc2_w     = (const float*)d_in[23];
  const float* fc2_b     = (const float*)d_in[24];

  // ---- workspace plan: PEAK 11,239,424 bytes (10.72 MiB) ----
  // A [0,3211264):        kv_raw bf16 rows (B,N,2C)   -> x2 fp32 (B,N,C flat) after attn
  // B [3211264,6422528):  kvp_raw bf16 rows (B,N,2C)  \_ f1b bf16 (682,N) per batch
  // C [6422528,8028160):  qs bf16 planes (B*nh*d, N)  /  [3211264,7488768) fits
  // D [8028160,9633792):  y bf16 rows -> xp bf16 rows -> y2 bf16 rows
  // E [9633792,11239424): q_raw bf16 rows -> xp_raw bf16 rows
  // xo: d_out (fp32, 802816 el) used as scratch; overwritten by fc2 at the end.
  char* w8 = (char*)d_ws;
  bf16*  kv_raw  = (bf16*)(w8 + 0);
  float* x2      = (float*)(w8 + 0);
  bf16*  kvp_raw = (bf16*)(w8 + 3211264);
  bf16*  f1b     = (bf16*)(w8 + 3211264);
  bf16*  qs      = (bf16*)(w8 + 6422528);
  bf16*  y       = (bf16*)(w8 + 8028160);
  bf16*  q_raw   = (bf16*)(w8 + 9633792);
  bf16*  xp_raw  = q_raw;
  bf16*  xp      = y;
  bf16*  y2      = y;
  float* xo      = (float*)d_out;

  // 1. y = LN1(x)   (fp32 planes -> bf16 rows)
  ln_kernel<float, bf16, true><<<ROWS_/4, 256, 0, stream>>>(x_in, norm1_w, norm1_b, y);
  // 2. q_raw = y @ q_w^T + q_b
  gemm_kernel<bf16, float, true, bf16, bf16><<<dim3(2,98), 256, 0, stream>>>(
      y, q_w, q_b, (const bf16*)nullptr, q_raw, ROWS_, 128, 128, 1);
  // 3. kv_raw = y @ kv_w^T + kv_b
  gemm_kernel<bf16, float, true, bf16, bf16><<<dim3(4,98), 256, 0, stream>>>(
      y, kv_w, kv_b, (const bf16*)nullptr, kv_raw, ROWS_, 256, 128, 1);
  // 4. qs planes
  post_q_kernel<<<98, 256, 0, stream>>>(q_raw, qe, temp, qs);
  // 5. xp_raw = gelu(y @ sr_w^T + sr_b)   (y dead after; writes over q_raw slot E)
  gemm_kernel<bf16, float, true, bf16, bf16><<<dim3(2,98), 256, 0, stream>>>(
      y, sr_w, sr_b, (const bf16*)nullptr, xp_raw, ROWS_, 128, 128, 2);
  // 6. xp = LN_pln(xp_raw)  (rows->rows, into slot D)
  ln_kernel<bf16, bf16, false><<<ROWS_/4, 256, 0, stream>>>(xp_raw, pln_w, pln_b, xp);
  // 7. kvp_raw = xp @ kv_w^T + kv_b
  gemm_kernel<bf16, float, true, bf16, bf16><<<dim3(4,98), 256, 0, stream>>>(
      xp, kv_w, kv_b, (const bf16*)nullptr, kvp_raw, ROWS_, 256, 128, 1);
  // 8. fused attention -> xo (d_out scratch, fp32, B,N,C rows)
  attn_fused_kernel<<<dim3(49,8), 256, 0, stream>>>(qs, kvp_raw, kv_raw, qe, temp, tokens, tbias, xo);
  // 9. x2 = x_in + (xo @ proj_w^T + proj_b)   (flat-reinterpret residual; fp32, slot A)
  gemm_kernel<float, float, true, float, float><<<dim3(2,98), 256, 0, stream>>>(
      xo, proj_w, proj_b, x_in, x2, ROWS_, 128, 128, 4);
  // 10. y2 = LN2(x2)  (fp32 planes -> bf16 rows, slot D)
  ln_kernel<float, bf16, true><<<ROWS_/4, 256, 0, stream>>>(x2, norm2_w, norm2_b, y2);
  // 11. MLP per batch
  for (int b = 0; b < B_; b++){
    // f1b = fc1_w @ y2_b^T + fc1_b  -> bf16 planes (682, N) in slots B+C
    gemm_kernel<float, bf16, true, bf16, bf16><<<dim3(49,11), 256, 0, stream>>>(
        fc1_w, y2 + (long)b*N_*C_, fc1_b, (const bf16*)nullptr, f1b, 2*HF_, N_, 128, 3);
    // gate in place: f1b[HF+c] = gelu(dw(f1b[c])+dw_b)*f1b[HF+c]
    dwconv_kernel<<<(HF_*N_ + 255)/256, 256, 0, stream>>>(f1b, dw_w, dw_b);
    // out_b = x2_b + fc2_w @ g + fc2_b  (fp32 out)
    gemm_kernel<float, bf16, false, float, float><<<dim3(49,2), 256, 0, stream>>>(
        fc2_w, f1b + (long)HF_*N_, fc2_b, x2 + (long)b*C_*N_,
        ((float*)d_out) + (long)b*C_*N_, C_, N_, HF_, 5);
  }
}

// Round 5
// 957.349 us; speedup vs baseline: 1.2878x; 1.2878x over previous
//
#include <hip/hip_runtime.h>
#include <hip/hip_bf16.h>

typedef __hip_bfloat16 bf16;

#define DEVI __device__ __forceinline__

DEVI float cvt(float x){ return x; }
DEVI float cvt(bf16 x){ return __bfloat162float(x); }

DEVI void stg(float* p, float v){ *p = v; }
DEVI void stg(bf16* p, float v){ *p = __float2bfloat16(v); }

DEVI float gelu_exact(float x){
  return 0.5f*x*(1.0f + erff(x*0.70710678118654752440f));
}

// problem constants
constexpr int B_ = 2, C_ = 128, H_ = 56, W_ = 56, N_ = 3136, NH_ = 4, D_ = 32, HF_ = 341;
constexpr int ROWS_ = B_*N_;             // 6272

// ---------------- LayerNorm (one wave per row of 128 channels) ----------------
template<typename TX, typename TY, bool PLANES>
__global__ __launch_bounds__(256)
void ln_kernel(const TX* __restrict__ x, const float* __restrict__ w,
               const float* __restrict__ bia, TY* __restrict__ y)
{
  int gid = blockIdx.x*4 + (threadIdx.x>>6);      // row over B*N
  int lane = threadIdx.x & 63;
  int b = gid / N_, n = gid % N_;
  float v0, v1;
  if (PLANES){
    v0 = cvt(x[((long)b*C_ + lane     )*N_ + n]);
    v1 = cvt(x[((long)b*C_ + lane + 64)*N_ + n]);
  } else {
    v0 = cvt(x[(long)gid*C_ + lane     ]);
    v1 = cvt(x[(long)gid*C_ + lane + 64]);
  }
  float s = v0+v1, ss = v0*v0 + v1*v1;
  #pragma unroll
  for (int o=32;o>0;o>>=1){ s += __shfl_xor(s,o); ss += __shfl_xor(ss,o); }
  float mu  = s*(1.0f/128.0f);
  float var = fmaxf(ss*(1.0f/128.0f) - mu*mu, 0.f);
  float inv = rsqrtf(var + 1e-5f);
  stg(&y[(long)gid*C_ + lane     ], (v0-mu)*inv*w[lane     ] + bia[lane     ]);
  stg(&y[(long)gid*C_ + lane + 64], (v1-mu)*inv*w[lane + 64] + bia[lane + 64]);
}

// ---------------- generic tiled GEMM ----------------
// out[m,n] = sum_k A[m,k] * (TRANSB ? B[n,k] : B[k,n])  (all row-major)
// mode: 1 = +bias[col], 2 = +bias[col]+gelu, 3 = +bias[row],
//       4 = +bias[col]+res[flat], 5 = +bias[row]+res[flat]
template<typename TA, typename TB, bool TRANSB, typename TC, typename TR>
__global__ __launch_bounds__(256)
void gemm_kernel(const TA* __restrict__ A, const TB* __restrict__ Bm,
                 const float* __restrict__ bias, const TR* __restrict__ res,
                 TC* __restrict__ Cm, int M, int Nn, int Kk, int mode)
{
  __shared__ float As[16][64];
  __shared__ float Bs[16][64];
  int tid = threadIdx.x;
  int tx = tid & 15, ty = tid >> 4;
  int m0 = blockIdx.y*64, n0 = blockIdx.x*64;
  float acc[4][4] = {};
  for (int k0 = 0; k0 < Kk; k0 += 16){
    #pragma unroll
    for (int i=0;i<4;i++){
      int idx = tid*4 + i;
      int mm = idx >> 4, kk = idx & 15;
      int gm = m0+mm, gk = k0+kk;
      As[kk][mm] = (gm<M && gk<Kk) ? cvt(A[(long)gm*Kk + gk]) : 0.f;
    }
    #pragma unroll
    for (int i=0;i<4;i++){
      if (TRANSB){
        int idx = tid*4 + i;
        int nn = idx >> 4, kk = idx & 15;
        int gn = n0+nn, gk = k0+kk;
        Bs[kk][nn] = (gn<Nn && gk<Kk) ? cvt(Bm[(long)gn*Kk + gk]) : 0.f;
      } else {
        int idx = tid + i*256;
        int kk = idx >> 6, nn = idx & 63;
        int gn = n0+nn, gk = k0+kk;
        Bs[kk][nn] = (gn<Nn && gk<Kk) ? cvt(Bm[(long)gk*Nn + gn]) : 0.f;
      }
    }
    __syncthreads();
    #pragma unroll
    for (int kk=0;kk<16;kk++){
      float a4[4], b4[4];
      #pragma unroll
      for (int i=0;i<4;i++) a4[i] = As[kk][ty*4+i];
      #pragma unroll
      for (int j=0;j<4;j++) b4[j] = Bs[kk][tx*4+j];
      #pragma unroll
      for (int i=0;i<4;i++)
        #pragma unroll
        for (int j=0;j<4;j++) acc[i][j] = fmaf(a4[i], b4[j], acc[i][j]);
    }
    __syncthreads();
  }
  #pragma unroll
  for (int i=0;i<4;i++){
    int gm = m0 + ty*4 + i;
    if (gm >= M) continue;
    #pragma unroll
    for (int j=0;j<4;j++){
      int gn = n0 + tx*4 + j;
      if (gn >= Nn) continue;
      float v = acc[i][j];
      if (mode==1 || mode==2 || mode==4) v += bias[gn];
      else                               v += bias[gm];
      if (mode==2) v = gelu_exact(v);
      if (mode==4 || mode==5) v += cvt(res[(long)gm*Nn + gn]);
      stg(&Cm[(long)gm*Nn + gn], v);
    }
  }
}

// ---------------- q post-process: l2n + embed + temperature -> qs planes ----------------
__global__ __launch_bounds__(256)
void post_q_kernel(const bf16* __restrict__ q_raw, const float* __restrict__ qe,
                   const float* __restrict__ temp, bf16* __restrict__ qs)
{
  int t = blockIdx.x*256 + threadIdx.x;        // (b*4+h)*N + n
  int n = t % N_; int bh = t / N_; int h = bh & 3; int b = bh >> 2;
  float sp = log1pf(expf(temp[h]));
  const bf16* qr = q_raw + ((long)(b*N_ + n))*C_ + h*D_;
  float v[32]; float ss = 0.f;
  #pragma unroll
  for (int d=0;d<32;d++){ v[d] = cvt(qr[d]); ss = fmaf(v[d], v[d], ss); }
  float inv = 1.f/fmaxf(sqrtf(ss), 1e-12f);
  #pragma unroll
  for (int d=0;d<32;d++)
    stg(&qs[((long)bh*D_ + d)*N_ + n], (v[d]*inv + qe[h*D_+d])*sp);
}

// ---------------- fused pool attention + local 3x3 + learnable tokens ----------------
// grid (25, 8); block 256 = 4 waves. Block owns 128 queries: lane L holds queries
// n0+L (A) and n0+64+L (B) -> each LDS K/V element is reused for 2 queries, and
// K/V rows are read as float4 (stride 36 floats keeps 16B alignment; broadcast
// reads are conflict-free). Waves split the 98 key-tiles 4-way (wave-private LDS);
// two-phase LDS merge at the end. exp shift -8 (softmax-invariant, exact).
__global__ __launch_bounds__(256, 1)
void attn_fused_kernel(const bf16* __restrict__ qs_, const bf16* __restrict__ kvp_,
                       const bf16* __restrict__ kv_,
                       const float* __restrict__ qe, const float* __restrict__ temp,
                       const float* __restrict__ tokens, const float* __restrict__ tbias,
                       float* __restrict__ xo)
{
  int bh = blockIdx.y; int h = bh & 3; int b = bh >> 2;
  int lane = threadIdx.x & 63;
  int w    = threadIdx.x >> 6;
  int n0 = blockIdx.x*128;
  int nA = n0 + lane;                            // always < N_ (3072+63 max)
  int nB = n0 + 64 + lane;                       // may exceed N_ in last block
  int nBc = min(nB, N_-1);
  const bf16* qsp = qs_ + (long)bh*D_*N_;
  float qa[32], qb[32];
  #pragma unroll
  for (int d=0;d<32;d++){
    qa[d] = cvt(qsp[(long)d*N_ + nA]);
    qb[d] = cvt(qsp[(long)d*N_ + nBc]);
  }
  __shared__ float sm[4][2336];                  // per wave: K 32x36 | V 32x36 | invnorm 32 (merge reuses)
  float* Ks = sm[w];
  float* Vs = Ks + 1152;
  float* Ns = Ks + 2304;
  const bf16* kvpb = kvp_ + (long)b*N_*(2*C_) + h*D_;   // rows (N,256), head offset
  int lo = (w<2) ? w*25 : 50 + (w-2)*24;         // 25/25/24/24 of 98 tiles
  int hi = (w<2) ? lo+25 : lo+24;
  float la = 0.f, lb = 0.f, acca[32], accb[32];
  #pragma unroll
  for (int d=0;d<32;d++){ acca[d]=0.f; accb[d]=0.f; }
  for (int tile=lo; tile<hi; tile++){            // wave-private: no block barrier needed
    int t0 = tile*32;
    #pragma unroll
    for (int i=0;i<16;i++){
      int idx = lane + i*64;
      int mm = idx >> 5, dd = idx & 31;
      Ks[mm*36+dd] = cvt(kvpb[(long)(t0+mm)*(2*C_) + dd]);
      Vs[mm*36+dd] = cvt(kvpb[(long)(t0+mm)*(2*C_) + C_ + dd]);
    }
    if (lane < 32){                              // inline l2-norm of the 32 pool keys
      float ss = 0.f;
      #pragma unroll
      for (int d=0;d<32;d++){ float kk = Ks[lane*36+d]; ss = fmaf(kk,kk,ss); }
      Ns[lane] = 1.f/fmaxf(sqrtf(ss), 1e-12f);
    }
    #pragma unroll 2
    for (int mm=0;mm<32;mm++){
      const float4* K4 = (const float4*)(Ks + mm*36);
      float s0 = 0.f, s1 = 0.f;
      #pragma unroll
      for (int i=0;i<8;i++){
        float4 k4 = K4[i];
        s0 = fmaf(qa[4*i+0],k4.x,s0); s0 = fmaf(qa[4*i+1],k4.y,s0);
        s0 = fmaf(qa[4*i+2],k4.z,s0); s0 = fmaf(qa[4*i+3],k4.w,s0);
        s1 = fmaf(qb[4*i+0],k4.x,s1); s1 = fmaf(qb[4*i+1],k4.y,s1);
        s1 = fmaf(qb[4*i+2],k4.z,s1); s1 = fmaf(qb[4*i+3],k4.w,s1);
      }
      float ni = Ns[mm];
      float e0 = __expf(fmaf(s0, ni, -8.f));
      float e1 = __expf(fmaf(s1, ni, -8.f));
      la += e0; lb += e1;
      const float4* V4 = (const float4*)(Vs + mm*36);
      #pragma unroll
      for (int i=0;i<8;i++){
        float4 v4 = V4[i];
        acca[4*i+0] = fmaf(e0,v4.x,acca[4*i+0]); acca[4*i+1] = fmaf(e0,v4.y,acca[4*i+1]);
        acca[4*i+2] = fmaf(e0,v4.z,acca[4*i+2]); acca[4*i+3] = fmaf(e0,v4.w,acca[4*i+3]);
        accb[4*i+0] = fmaf(e1,v4.x,accb[4*i+0]); accb[4*i+1] = fmaf(e1,v4.y,accb[4*i+1]);
        accb[4*i+2] = fmaf(e1,v4.z,accb[4*i+2]); accb[4*i+3] = fmaf(e1,v4.w,accb[4*i+3]);
      }
    }
  }
  // two-phase merge of 4 wave-partials (reuse sm; region per wave 2112 <= 2336)
  const bf16* kvb = kv_ + (long)b*N_*(2*C_) + h*D_;
  float sp = log1pf(expf(temp[h]));
  float invsp = 1.f/sp;
  #pragma unroll
  for (int p=0;p<2;p++){
    __syncthreads();
    {
      float* red = sm[w];
      red[lane] = p ? lb : la;
      float* accp = p ? accb : acca;
      #pragma unroll
      for (int d=0;d<32;d++) red[(1+d)*64 + lane] = accp[d];
    }
    __syncthreads();
    if (threadIdx.x < 64){
      int nq = n0 + p*64 + lane;
      if (nq < N_){
        float L = 0.f, out[32];
        #pragma unroll
        for (int d=0;d<32;d++) out[d]=0.f;
        #pragma unroll
        for (int ww=0;ww<4;ww++){
          L += sm[ww][lane];
          #pragma unroll
          for (int d=0;d<32;d++) out[d] += sm[ww][(1+d)*64 + lane];
        }
        const float* q = p ? qb : qa;            // wave 0 holds the same queries
        // local 3x3: keys/values from kv_raw rows, keys normalized inline.
        // Zero-padded (OOB) keys score exactly 0 (stay in softmax denominator).
        int hy = nq / W_, wx = nq % W_;
        float sl[9];
        #pragma unroll
        for (int k=0;k<9;k++){
          int di = k/3-1, dj = k%3-1;
          int yy = hy+di, xx = wx+dj;
          float s = 0.f;
          if (yy>=0 && yy<H_ && xx>=0 && xx<W_){
            long nn2 = (long)(yy*W_+xx)*(2*C_);
            float dot = 0.f, ss = 0.f;
            #pragma unroll
            for (int d=0;d<32;d++){
              float kk = cvt(kvb[nn2 + d]);
              dot = fmaf(q[d], kk, dot);
              ss  = fmaf(kk, kk, ss);
            }
            s = dot / fmaxf(sqrtf(ss), 1e-12f);
          }
          sl[k] = s;
        }
        #pragma unroll
        for (int k=0;k<9;k++) L += __expf(sl[k] - 8.f);
        float invL = 1.f/L;
        #pragma unroll
        for (int d=0;d<32;d++) out[d] *= invL;
        float qn[32];
        #pragma unroll
        for (int d=0;d<32;d++) qn[d] = q[d]*invsp - qe[h*D_+d];
        #pragma unroll
        for (int k=0;k<9;k++){
          float tok = 0.f;
          #pragma unroll
          for (int d=0;d<32;d++) tok = fmaf(qn[d], tokens[(h*D_+d)*9+k], tok);
          float wl = tok + tbias[h*9+k] + __expf(sl[k] - 8.f)*invL;
          int di = k/3-1, dj = k%3-1;
          int yy = hy+di, xx = wx+dj;
          if (yy>=0 && yy<H_ && xx>=0 && xx<W_){ // OOB v_l zero-padded -> contributes 0
            long nn2 = (long)(yy*W_+xx)*(2*C_);
            #pragma unroll
            for (int d=0;d<32;d++) out[d] = fmaf(wl, cvt(kvb[nn2 + C_ + d]), out[d]);
          }
        }
        float* op = xo + ((long)(b*N_ + nq))*C_ + h*D_;   // (B,N,C) rows
        #pragma unroll
        for (int d=0;d<32;d++) op[d] = out[d];
      }
    }
  }
}

// ---------------- depthwise 3x3 conv + bias + gelu, gate IN-PLACE over v ----------------
// one batch; f1 = planes (2*HF, N) bf16. g[c,n] = gelu(dw(a)[c,n]+b[c]) * f1[HF+c,n],
// written over f1[HF+c,n] (each element read only by its own thread -> race-free).
__global__ __launch_bounds__(256)
void dwconv_kernel(bf16* __restrict__ f1, const float* __restrict__ dww,
                   const float* __restrict__ dwb)
{
  int t = blockIdx.x*256 + threadIdx.x;
  if (t >= HF_*N_) return;
  int n = t % N_; int c = t / N_;
  int hy = n / W_, wx = n % W_;
  const bf16* ap = f1 + (long)c*N_;
  float s = dwb[c];
  #pragma unroll
  for (int di=-1; di<=1; di++)
    #pragma unroll
    for (int dj=-1; dj<=1; dj++){
      int yy = hy+di, xx = wx+dj;
      if (yy>=0 && yy<H_ && xx>=0 && xx<W_)
        s = fmaf(dww[c*9 + (di+1)*3 + (dj+1)], cvt(ap[yy*W_+xx]), s);
    }
  float ge = gelu_exact(s);
  long vi = ((long)(HF_+c))*N_ + n;
  stg(&f1[vi], ge*cvt(f1[vi]));
}

// ---------------- launcher ----------------
extern "C" void kernel_launch(void* const* d_in, const int* in_sizes, int n_in,
                              void* d_out, int out_size, void* d_ws, size_t ws_size,
                              hipStream_t stream)
{
  (void)in_sizes; (void)n_in; (void)out_size; (void)ws_size;
  // Reference setup_inputs() is jnp.float32 for every tensor -> fp32 pointers.
  const float* x_in      = (const float*)d_in[0];
  const float* norm1_w   = (const float*)d_in[1];
  const float* norm1_b   = (const float*)d_in[2];
  const float* q_w       = (const float*)d_in[3];
  const float* q_b       = (const float*)d_in[4];
  const float* kv_w      = (const float*)d_in[5];
  const float* kv_b      = (const float*)d_in[6];
  const float* temp      = (const float*)d_in[7];
  const float* qe        = (const float*)d_in[8];
  const float* tokens    = (const float*)d_in[9];
  const float* tbias     = (const float*)d_in[10];
  const float* sr_w      = (const float*)d_in[11];
  const float* sr_b      = (const float*)d_in[12];
  const float* pln_w     = (const float*)d_in[13];
  const float* pln_b     = (const float*)d_in[14];
  const float* proj_w    = (const float*)d_in[15];
  const float* proj_b    = (const float*)d_in[16];
  const float* norm2_w   = (const float*)d_in[17];
  const float* norm2_b   = (const float*)d_in[18];
  const float* fc1_w     = (const float*)d_in[19];
  const float* fc1_b     = (const float*)d_in[20];
  const float* dw_w      = (const float*)d_in[21];
  const float* dw_b      = (const float*)d_in[22];
  const float* fc2_w     = (const float*)d_in[23];
  const float* fc2_b     = (const float*)d_in[24];

  // ---- workspace plan: PEAK 11,239,424 bytes (10.72 MiB) ----
  // A [0,3211264):        kv_raw bf16 rows (B,N,2C)   -> x2 fp32 (B,N,C flat) after attn
  // B [3211264,6422528):  kvp_raw bf16 rows (B,N,2C)  \_ f1b bf16 (682,N) per batch
  // C [6422528,8028160):  qs bf16 planes (B*nh*d, N)  /  [3211264,7488768) fits
  // D [8028160,9633792):  y bf16 rows -> xp bf16 rows -> y2 bf16 rows
  // E [9633792,11239424): q_raw bf16 rows -> xp_raw bf16 rows
  // xo: d_out (fp32, 802816 el) used as scratch; overwritten by fc2 at the end.
  char* w8 = (char*)d_ws;
  bf16*  kv_raw  = (bf16*)(w8 + 0);
  float* x2      = (float*)(w8 + 0);
  bf16*  kvp_raw = (bf16*)(w8 + 3211264);
  bf16*  f1b     = (bf16*)(w8 + 3211264);
  bf16*  qs      = (bf16*)(w8 + 6422528);
  bf16*  y       = (bf16*)(w8 + 8028160);
  bf16*  q_raw   = (bf16*)(w8 + 9633792);
  bf16*  xp_raw  = q_raw;
  bf16*  xp      = y;
  bf16*  y2      = y;
  float* xo      = (float*)d_out;

  // 1. y = LN1(x)   (fp32 planes -> bf16 rows)
  ln_kernel<float, bf16, true><<<ROWS_/4, 256, 0, stream>>>(x_in, norm1_w, norm1_b, y);
  // 2. q_raw = y @ q_w^T + q_b
  gemm_kernel<bf16, float, true, bf16, bf16><<<dim3(2,98), 256, 0, stream>>>(
      y, q_w, q_b, (const bf16*)nullptr, q_raw, ROWS_, 128, 128, 1);
  // 3. kv_raw = y @ kv_w^T + kv_b
  gemm_kernel<bf16, float, true, bf16, bf16><<<dim3(4,98), 256, 0, stream>>>(
      y, kv_w, kv_b, (const bf16*)nullptr, kv_raw, ROWS_, 256, 128, 1);
  // 4. qs planes
  post_q_kernel<<<98, 256, 0, stream>>>(q_raw, qe, temp, qs);
  // 5. xp_raw = gelu(y @ sr_w^T + sr_b)   (y dead after; writes over q_raw slot E)
  gemm_kernel<bf16, float, true, bf16, bf16><<<dim3(2,98), 256, 0, stream>>>(
      y, sr_w, sr_b, (const bf16*)nullptr, xp_raw, ROWS_, 128, 128, 2);
  // 6. xp = LN_pln(xp_raw)  (rows->rows, into slot D)
  ln_kernel<bf16, bf16, false><<<ROWS_/4, 256, 0, stream>>>(xp_raw, pln_w, pln_b, xp);
  // 7. kvp_raw = xp @ kv_w^T + kv_b
  gemm_kernel<bf16, float, true, bf16, bf16><<<dim3(4,98), 256, 0, stream>>>(
      xp, kv_w, kv_b, (const bf16*)nullptr, kvp_raw, ROWS_, 256, 128, 1);
  // 8. fused attention -> xo (d_out scratch, fp32, B,N,C rows)
  attn_fused_kernel<<<dim3(25,8), 256, 0, stream>>>(qs, kvp_raw, kv_raw, qe, temp, tokens, tbias, xo);
  // 9. x2 = x_in + (xo @ proj_w^T + proj_b)   (flat-reinterpret residual; fp32, slot A)
  gemm_kernel<float, float, true, float, float><<<dim3(2,98), 256, 0, stream>>>(
      xo, proj_w, proj_b, x_in, x2, ROWS_, 128, 128, 4);
  // 10. y2 = LN2(x2)  (fp32 planes -> bf16 rows, slot D)
  ln_kernel<float, bf16, true><<<ROWS_/4, 256, 0, stream>>>(x2, norm2_w, norm2_b, y2);
  // 11. MLP per batch
  for (int b = 0; b < B_; b++){
    // f1b = fc1_w @ y2_b^T + fc1_b  -> bf16 planes (682, N) in slots B+C
    gemm_kernel<float, bf16, true, bf16, bf16><<<dim3(49,11), 256, 0, stream>>>(
        fc1_w, y2 + (long)b*N_*C_, fc1_b, (const bf16*)nullptr, f1b, 2*HF_, N_, 128, 3);
    // gate in place: f1b[HF+c] = gelu(dw(f1b[c])+dw_b)*f1b[HF+c]
    dwconv_kernel<<<(HF_*N_ + 255)/256, 256, 0, stream>>>(f1b, dw_w, dw_b);
    // out_b = x2_b + fc2_w @ g + fc2_b  (fp32 out)
    gemm_kernel<float, bf16, false, float, float><<<dim3(49,2), 256, 0, stream>>>(
        fc2_w, f1b + (long)HF_*N_, fc2_b, x2 + (long)b*C_*N_,
        ((float*)d_out) + (long)b*C_*N_, C_, N_, HF_, 5);
  }
}

// Round 6
// 505.885 us; speedup vs baseline: 2.4370x; 1.8924x over previous
//
#include <hip/hip_runtime.h>
#include <hip/hip_bf16.h>

typedef __hip_bfloat16 bf16;
typedef short s8v __attribute__((ext_vector_type(8)));   // 8 bf16 = 4 VGPR MFMA frag
typedef float f4v __attribute__((ext_vector_type(4)));   // 4 fp32 MFMA acc

#define DEVI __device__ __forceinline__

DEVI float cvt(float x){ return x; }
DEVI float cvt(bf16 x){ return __bfloat162float(x); }

DEVI void stg(float* p, float v){ *p = v; }
DEVI void stg(bf16* p, float v){ *p = __float2bfloat16(v); }

DEVI float gelu_exact(float x){
  return 0.5f*x*(1.0f + erff(x*0.70710678118654752440f));
}

// problem constants
constexpr int B_ = 2, C_ = 128, H_ = 56, W_ = 56, N_ = 3136, NH_ = 4, D_ = 32, HF_ = 341;
constexpr int ROWS_ = B_*N_;             // 6272

// ---------------- LayerNorm (one wave per row of 128 channels) ----------------
template<typename TX, typename TY, bool PLANES>
__global__ __launch_bounds__(256)
void ln_kernel(const TX* __restrict__ x, const float* __restrict__ w,
               const float* __restrict__ bia, TY* __restrict__ y)
{
  int gid = blockIdx.x*4 + (threadIdx.x>>6);      // row over B*N
  int lane = threadIdx.x & 63;
  int b = gid / N_, n = gid % N_;
  float v0, v1;
  if (PLANES){
    v0 = cvt(x[((long)b*C_ + lane     )*N_ + n]);
    v1 = cvt(x[((long)b*C_ + lane + 64)*N_ + n]);
  } else {
    v0 = cvt(x[(long)gid*C_ + lane     ]);
    v1 = cvt(x[(long)gid*C_ + lane + 64]);
  }
  float s = v0+v1, ss = v0*v0 + v1*v1;
  #pragma unroll
  for (int o=32;o>0;o>>=1){ s += __shfl_xor(s,o); ss += __shfl_xor(ss,o); }
  float mu  = s*(1.0f/128.0f);
  float var = fmaxf(ss*(1.0f/128.0f) - mu*mu, 0.f);
  float inv = rsqrtf(var + 1e-5f);
  stg(&y[(long)gid*C_ + lane     ], (v0-mu)*inv*w[lane     ] + bia[lane     ]);
  stg(&y[(long)gid*C_ + lane + 64], (v1-mu)*inv*w[lane + 64] + bia[lane + 64]);
}

// ---------------- generic tiled GEMM ----------------
// out[m,n] = sum_k A[m,k] * (TRANSB ? B[n,k] : B[k,n])  (all row-major)
// mode: 1 = +bias[col], 2 = +bias[col]+gelu, 3 = +bias[row],
//       4 = +bias[col]+res[flat], 5 = +bias[row]+res[flat]
template<typename TA, typename TB, bool TRANSB, typename TC, typename TR>
__global__ __launch_bounds__(256)
void gemm_kernel(const TA* __restrict__ A, const TB* __restrict__ Bm,
                 const float* __restrict__ bias, const TR* __restrict__ res,
                 TC* __restrict__ Cm, int M, int Nn, int Kk, int mode)
{
  __shared__ float As[16][64];
  __shared__ float Bs[16][64];
  int tid = threadIdx.x;
  int tx = tid & 15, ty = tid >> 4;
  int m0 = blockIdx.y*64, n0 = blockIdx.x*64;
  float acc[4][4] = {};
  for (int k0 = 0; k0 < Kk; k0 += 16){
    #pragma unroll
    for (int i=0;i<4;i++){
      int idx = tid*4 + i;
      int mm = idx >> 4, kk = idx & 15;
      int gm = m0+mm, gk = k0+kk;
      As[kk][mm] = (gm<M && gk<Kk) ? cvt(A[(long)gm*Kk + gk]) : 0.f;
    }
    #pragma unroll
    for (int i=0;i<4;i++){
      if (TRANSB){
        int idx = tid*4 + i;
        int nn = idx >> 4, kk = idx & 15;
        int gn = n0+nn, gk = k0+kk;
        Bs[kk][nn] = (gn<Nn && gk<Kk) ? cvt(Bm[(long)gn*Kk + gk]) : 0.f;
      } else {
        int idx = tid + i*256;
        int kk = idx >> 6, nn = idx & 63;
        int gn = n0+nn, gk = k0+kk;
        Bs[kk][nn] = (gn<Nn && gk<Kk) ? cvt(Bm[(long)gk*Nn + gn]) : 0.f;
      }
    }
    __syncthreads();
    #pragma unroll
    for (int kk=0;kk<16;kk++){
      float a4[4], b4[4];
      #pragma unroll
      for (int i=0;i<4;i++) a4[i] = As[kk][ty*4+i];
      #pragma unroll
      for (int j=0;j<4;j++) b4[j] = Bs[kk][tx*4+j];
      #pragma unroll
      for (int i=0;i<4;i++)
        #pragma unroll
        for (int j=0;j<4;j++) acc[i][j] = fmaf(a4[i], b4[j], acc[i][j]);
    }
    __syncthreads();
  }
  #pragma unroll
  for (int i=0;i<4;i++){
    int gm = m0 + ty*4 + i;
    if (gm >= M) continue;
    #pragma unroll
    for (int j=0;j<4;j++){
      int gn = n0 + tx*4 + j;
      if (gn >= Nn) continue;
      float v = acc[i][j];
      if (mode==1 || mode==2 || mode==4) v += bias[gn];
      else                               v += bias[gm];
      if (mode==2) v = gelu_exact(v);
      if (mode==4 || mode==5) v += cvt(res[(long)gm*Nn + gn]);
      stg(&Cm[(long)gm*Nn + gn], v);
    }
  }
}

// ---------------- q post-process: l2n + embed + temperature -> qs ROWS ----------------
// qs rows (bh, n, 32) bf16: contiguous per query for MFMA A-frags + epilogue.
__global__ __launch_bounds__(256)
void post_q_kernel(const bf16* __restrict__ q_raw, const float* __restrict__ qe,
                   const float* __restrict__ temp, bf16* __restrict__ qs)
{
  int t = blockIdx.x*256 + threadIdx.x;        // (b*4+h)*N + n
  int n = t % N_; int bh = t / N_; int h = bh & 3; int b = bh >> 2;
  float sp = log1pf(expf(temp[h]));
  const bf16* qr = q_raw + ((long)(b*N_ + n))*C_ + h*D_;
  float v[32]; float ss = 0.f;
  #pragma unroll
  for (int d=0;d<32;d++){ v[d] = cvt(qr[d]); ss = fmaf(v[d], v[d], ss); }
  float inv = 1.f/fmaxf(sqrtf(ss), 1e-12f);
  bf16* qo = qs + ((long)bh*N_ + n)*D_;
  #pragma unroll
  for (int d=0;d<32;d++)
    stg(&qo[d], (v[d]*inv + qe[h*D_+d])*sp);
}

// ---------------- pooled kv post-process ----------------
// k_p: normalized key ROWS (bh, n, 32) bf16 -> QK B-frags (8 consecutive dims/lane)
// v_p: value PLANES (bh, d, N) bf16        -> PV B-frags (8 consecutive keys/lane)
__global__ __launch_bounds__(256)
void post_kvp_kernel(const bf16* __restrict__ kvp_raw,
                     bf16* __restrict__ kp, bf16* __restrict__ vp)
{
  int t = blockIdx.x*256 + threadIdx.x;        // bh*N + n
  int n = t % N_; int bh = t / N_; int h = bh & 3; int b = bh >> 2;
  const bf16* kr = kvp_raw + ((long)(b*N_ + n))*(2*C_) + h*D_;
  float v[32]; float ss = 0.f;
  #pragma unroll
  for (int d=0;d<32;d++){ v[d] = cvt(kr[d]); ss = fmaf(v[d], v[d], ss); }
  float inv = 1.f/fmaxf(sqrtf(ss), 1e-12f);
  bf16* ko = kp + ((long)bh*N_ + n)*D_;
  #pragma unroll
  for (int d=0;d<32;d++) stg(&ko[d], v[d]*inv);
  #pragma unroll
  for (int d=0;d<32;d++) vp[((long)bh*D_ + d)*N_ + n] = kr[C_ + d];
}

// ---------------- MFMA fused attention ----------------
// grid (49, 8); block 256 = 4 waves; wave w owns queries q0 = bx*64 + w*16 .. +16.
// Everything wave-private (no __syncthreads). Per 64-key tile:
//   S(16x64) = 4x mfma_16x16x32_bf16 (A = Q rows frag, B = k_p rows frag)
//   P = exp(S - 8)  (scores bounded; shift softmax-invariant) ; L via lane partials
//   P -> LDS (C-layout write, A-layout b128 read), O(16x32) += 4x mfma with v_p planes
// Epilogue: O,L -> LDS; lane remap (query=lane&15, dimgroup=lane>>4); local 3x3 part
// with 4-lane split dot products reduced via shfl_xor(16|32); write xo rows.
__global__ __launch_bounds__(256)
void attn_mfma_kernel(const bf16* __restrict__ qs_, const bf16* __restrict__ kp_,
                      const bf16* __restrict__ vp_, const bf16* __restrict__ kv_,
                      const float* __restrict__ qe, const float* __restrict__ temp,
                      const float* __restrict__ tokens, const float* __restrict__ tbias,
                      float* __restrict__ xo)
{
  int bh = blockIdx.y; int h = bh & 3; int b = bh >> 2;
  int lane = threadIdx.x & 63;
  int w    = threadIdx.x >> 6;
  int m    = lane & 15, quad = lane >> 4;
  int q0   = blockIdx.x*64 + w*16;
  __shared__ float sm[4][608];                 // per-wave union: P 16x72 bf16 | O 16x36 f32 + L 16
  bf16*  Plds = (bf16*)sm[w];
  float* Olds = sm[w];

  // A-frag: Q[q0+m][quad*8 .. +8]  (row of qs rows, 16B)
  s8v afrag = *(const s8v*)(qs_ + ((long)bh*N_ + q0 + m)*D_ + quad*8);
  const bf16* kpb = kp_ + (long)bh*N_*D_;
  const bf16* vpb = vp_ + (long)bh*D_*N_;
  f4v oacc0 = {0.f,0.f,0.f,0.f}, oacc1 = {0.f,0.f,0.f,0.f};
  float lacc[4] = {0.f,0.f,0.f,0.f};

  for (int t0 = 0; t0 < N_; t0 += 64){
    float p[4][4];
    #pragma unroll
    for (int s = 0; s < 4; s++){
      s8v bfrag = *(const s8v*)(kpb + (long)(t0 + s*16 + m)*D_ + quad*8);
      f4v c = {0.f,0.f,0.f,0.f};
      c = __builtin_amdgcn_mfma_f32_16x16x32_bf16(afrag, bfrag, c, 0, 0, 0);
      #pragma unroll
      for (int r=0;r<4;r++){
        float e = __expf(c[r] - 8.f);          // D: row=quad*4+r (query), col=m (key)
        lacc[r] += e;
        p[s][r] = e;
      }
    }
    // P -> LDS bf16, row=query (quad*4+r), col=key (s*16+m), stride 72 (144B, 16B-mult)
    #pragma unroll
    for (int s=0;s<4;s++)
      #pragma unroll
      for (int r=0;r<4;r++)
        Plds[(quad*4+r)*72 + s*16 + m] = __float2bfloat16(p[s][r]);
    // PV: A = P[m][c2*32 + quad*8 ..], B = v_p[dim][t0 + c2*32 + quad*8 ..]
    #pragma unroll
    for (int c2=0;c2<2;c2++){
      s8v pa  = *(const s8v*)(Plds + m*72 + c2*32 + quad*8);
      s8v vb0 = *(const s8v*)(vpb + (long)(m     )*N_ + t0 + c2*32 + quad*8);
      s8v vb1 = *(const s8v*)(vpb + (long)(16 + m)*N_ + t0 + c2*32 + quad*8);
      oacc0 = __builtin_amdgcn_mfma_f32_16x16x32_bf16(pa, vb0, oacc0, 0, 0, 0);
      oacc1 = __builtin_amdgcn_mfma_f32_16x16x32_bf16(pa, vb1, oacc1, 0, 0, 0);
    }
  }
  // L: reduce lane partials over the 16 lanes of each quad
  #pragma unroll
  for (int off=1; off<16; off<<=1)
    #pragma unroll
    for (int r=0;r<4;r++) lacc[r] += __shfl_xor(lacc[r], off);
  // dump O (stride 36 f32) + L (at 576) to wave LDS
  #pragma unroll
  for (int r=0;r<4;r++){
    Olds[(quad*4+r)*36 + m     ] = oacc0[r];
    Olds[(quad*4+r)*36 + 16 + m] = oacc1[r];
  }
  if (m == 0){
    #pragma unroll
    for (int r=0;r<4;r++) Olds[576 + quad*4 + r] = lacc[r];
  }
  // ---- epilogue: lane -> (query m, dim-group quad) ----
  int nq = q0 + m;
  int dg = quad;                                // dims dg*8 .. +8
  f4v ov0 = *(const f4v*)(Olds + m*36 + dg*8);
  f4v ov1 = *(const f4v*)(Olds + m*36 + dg*8 + 4);
  float Lp = Olds[576 + m];
  float sp = log1pf(expf(temp[h]));
  float invsp = 1.f/sp;
  float q8[8], qn8[8];
  const bf16* qrow8 = qs_ + ((long)bh*N_ + nq)*D_ + dg*8;
  #pragma unroll
  for (int j=0;j<8;j++){
    q8[j]  = cvt(qrow8[j]);
    qn8[j] = q8[j]*invsp - qe[h*D_ + dg*8 + j];
  }
  int hy = nq / W_, wx = nq % W_;
  const bf16* kvb = kv_ + (long)b*N_*(2*C_) + h*D_ + dg*8;        // key part, my dims
  const bf16* vvb = kvb + C_;                                     // value part, my dims
  float Ltot = Lp;
  float sl[9], tk[9];
  #pragma unroll
  for (int k=0;k<9;k++){
    int di = k/3-1, dj = k%3-1;
    int yy = hy+di, xx = wx+dj;
    bool inb = (yy>=0 && yy<H_ && xx>=0 && xx<W_);
    float dotp = 0.f, ssp = 0.f, tokp = 0.f;
    if (inb){
      const bf16* kr = kv_ + (long)b*N_*(2*C_) + (long)(yy*W_+xx)*(2*C_) + h*D_ + dg*8;
      #pragma unroll
      for (int j=0;j<8;j++){
        float kk = cvt(kr[j]);
        dotp = fmaf(q8[j], kk, dotp);
        ssp  = fmaf(kk, kk, ssp);
      }
    }
    #pragma unroll
    for (int j=0;j<8;j++) tokp = fmaf(qn8[j], tokens[(h*D_ + dg*8 + j)*9 + k], tokp);
    // reduce partials over the 4 lanes (same query, different dim-groups)
    dotp += __shfl_xor(dotp,16); dotp += __shfl_xor(dotp,32);
    ssp  += __shfl_xor(ssp ,16); ssp  += __shfl_xor(ssp ,32);
    tokp += __shfl_xor(tokp,16); tokp += __shfl_xor(tokp,32);
    float s = dotp / fmaxf(sqrtf(ssp), 1e-12f);   // OOB: 0/1e-12 = 0 (zero-padded key)
    sl[k] = s; tk[k] = tokp;
    Ltot += __expf(s - 8.f);
  }
  float invL = 1.f/Ltot;
  float out8[8];
  #pragma unroll
  for (int j=0;j<4;j++){ out8[j] = ov0[j]*invL; out8[4+j] = ov1[j]*invL; }
  #pragma unroll
  for (int k=0;k<9;k++){
    int di = k/3-1, dj = k%3-1;
    int yy = hy+di, xx = wx+dj;
    float wl = tk[k] + tbias[h*9+k] + __expf(sl[k] - 8.f)*invL;
    if (yy>=0 && yy<H_ && xx>=0 && xx<W_){       // OOB v_l zero-padded -> contributes 0
      const bf16* vr = kv_ + (long)b*N_*(2*C_) + (long)(yy*W_+xx)*(2*C_) + C_ + h*D_ + dg*8;
      #pragma unroll
      for (int j=0;j<8;j++) out8[j] = fmaf(wl, cvt(vr[j]), out8[j]);
    }
  }
  float* op = xo + ((long)(b*N_ + nq))*C_ + h*D_ + dg*8;
  *(float4*)(op)     = make_float4(out8[0], out8[1], out8[2], out8[3]);
  *(float4*)(op + 4) = make_float4(out8[4], out8[5], out8[6], out8[7]);
}

// ---------------- depthwise 3x3 conv + bias + gelu, gate IN-PLACE over v ----------------
__global__ __launch_bounds__(256)
void dwconv_kernel(bf16* __restrict__ f1, const float* __restrict__ dww,
                   const float* __restrict__ dwb)
{
  int t = blockIdx.x*256 + threadIdx.x;
  if (t >= HF_*N_) return;
  int n = t % N_; int c = t / N_;
  int hy = n / W_, wx = n % W_;
  const bf16* ap = f1 + (long)c*N_;
  float s = dwb[c];
  #pragma unroll
  for (int di=-1; di<=1; di++)
    #pragma unroll
    for (int dj=-1; dj<=1; dj++){
      int yy = hy+di, xx = wx+dj;
      if (yy>=0 && yy<H_ && xx>=0 && xx<W_)
        s = fmaf(dww[c*9 + (di+1)*3 + (dj+1)], cvt(ap[yy*W_+xx]), s);
    }
  float ge = gelu_exact(s);
  long vi = ((long)(HF_+c))*N_ + n;
  stg(&f1[vi], ge*cvt(f1[vi]));
}

// ---------------- launcher ----------------
extern "C" void kernel_launch(void* const* d_in, const int* in_sizes, int n_in,
                              void* d_out, int out_size, void* d_ws, size_t ws_size,
                              hipStream_t stream)
{
  (void)in_sizes; (void)n_in; (void)out_size; (void)ws_size;
  const float* x_in      = (const float*)d_in[0];
  const float* norm1_w   = (const float*)d_in[1];
  const float* norm1_b   = (const float*)d_in[2];
  const float* q_w       = (const float*)d_in[3];
  const float* q_b       = (const float*)d_in[4];
  const float* kv_w      = (const float*)d_in[5];
  const float* kv_b      = (const float*)d_in[6];
  const float* temp      = (const float*)d_in[7];
  const float* qe        = (const float*)d_in[8];
  const float* tokens    = (const float*)d_in[9];
  const float* tbias     = (const float*)d_in[10];
  const float* sr_w      = (const float*)d_in[11];
  const float* sr_b      = (const float*)d_in[12];
  const float* pln_w     = (const float*)d_in[13];
  const float* pln_b     = (const float*)d_in[14];
  const float* proj_w    = (const float*)d_in[15];
  const float* proj_b    = (const float*)d_in[16];
  const float* norm2_w   = (const float*)d_in[17];
  const float* norm2_b   = (const float*)d_in[18];
  const float* fc1_w     = (const float*)d_in[19];
  const float* fc1_b     = (const float*)d_in[20];
  const float* dw_w      = (const float*)d_in[21];
  const float* dw_b      = (const float*)d_in[22];
  const float* fc2_w     = (const float*)d_in[23];
  const float* fc2_b     = (const float*)d_in[24];

  // ---- workspace plan: PEAK 11,239,424 bytes (10.72 MiB) ----
  // A [0,3211264):        kv_raw bf16 rows (B,N,2C)   -> x2 fp32 (B,N,C flat) after attn
  // B [3211264,6422528):  kvp_raw bf16 rows (B,N,2C)  \_ f1b bf16 (682,N) per batch
  // C [6422528,8028160):  qs bf16 ROWS (bh,N,32)      /  [3211264,7488768) fits
  // D [8028160,9633792):  y bf16 rows -> xp bf16 rows -> k_p bf16 rows -> y2 bf16 rows
  // E [9633792,11239424): q_raw bf16 rows -> xp_raw bf16 rows -> v_p bf16 planes
  // xo: d_out (fp32, 802816 el) used as scratch; overwritten by fc2 at the end.
  char* w8 = (char*)d_ws;
  bf16*  kv_raw  = (bf16*)(w8 + 0);
  float* x2      = (float*)(w8 + 0);
  bf16*  kvp_raw = (bf16*)(w8 + 3211264);
  bf16*  f1b     = (bf16*)(w8 + 3211264);
  bf16*  qs      = (bf16*)(w8 + 6422528);
  bf16*  y       = (bf16*)(w8 + 8028160);
  bf16*  q_raw   = (bf16*)(w8 + 9633792);
  bf16*  xp_raw  = q_raw;
  bf16*  xp      = y;
  bf16*  k_p     = y;        // after xp is consumed
  bf16*  v_p     = q_raw;    // after xp_raw is consumed
  bf16*  y2      = y;
  float* xo      = (float*)d_out;

  // 1. y = LN1(x)
  ln_kernel<float, bf16, true><<<ROWS_/4, 256, 0, stream>>>(x_in, norm1_w, norm1_b, y);
  // 2. q_raw = y @ q_w^T + q_b
  gemm_kernel<bf16, float, true, bf16, bf16><<<dim3(2,98), 256, 0, stream>>>(
      y, q_w, q_b, (const bf16*)nullptr, q_raw, ROWS_, 128, 128, 1);
  // 3. kv_raw = y @ kv_w^T + kv_b
  gemm_kernel<bf16, float, true, bf16, bf16><<<dim3(4,98), 256, 0, stream>>>(
      y, kv_w, kv_b, (const bf16*)nullptr, kv_raw, ROWS_, 256, 128, 1);
  // 4. qs rows
  post_q_kernel<<<98, 256, 0, stream>>>(q_raw, qe, temp, qs);
  // 5. xp_raw = gelu(y @ sr_w^T + sr_b)
  gemm_kernel<bf16, float, true, bf16, bf16><<<dim3(2,98), 256, 0, stream>>>(
      y, sr_w, sr_b, (const bf16*)nullptr, xp_raw, ROWS_, 128, 128, 2);
  // 6. xp = LN_pln(xp_raw)
  ln_kernel<bf16, bf16, false><<<ROWS_/4, 256, 0, stream>>>(xp_raw, pln_w, pln_b, xp);
  // 7. kvp_raw = xp @ kv_w^T + kv_b
  gemm_kernel<bf16, float, true, bf16, bf16><<<dim3(4,98), 256, 0, stream>>>(
      xp, kv_w, kv_b, (const bf16*)nullptr, kvp_raw, ROWS_, 256, 128, 1);
  // 7.5 k_p rows (normalized) -> slot D, v_p planes -> slot E
  post_kvp_kernel<<<98, 256, 0, stream>>>(kvp_raw, k_p, v_p);
  // 8. MFMA fused attention -> xo (d_out scratch, fp32, B,N,C rows)
  attn_mfma_kernel<<<dim3(49,8), 256, 0, stream>>>(qs, k_p, v_p, kv_raw, qe, temp, tokens, tbias, xo);
  // 9. x2 = x_in + (xo @ proj_w^T + proj_b)
  gemm_kernel<float, float, true, float, float><<<dim3(2,98), 256, 0, stream>>>(
      xo, proj_w, proj_b, x_in, x2, ROWS_, 128, 128, 4);
  // 10. y2 = LN2(x2)
  ln_kernel<float, bf16, true><<<ROWS_/4, 256, 0, stream>>>(x2, norm2_w, norm2_b, y2);
  // 11. MLP per batch
  for (int b = 0; b < B_; b++){
    gemm_kernel<float, bf16, true, bf16, bf16><<<dim3(49,11), 256, 0, stream>>>(
        fc1_w, y2 + (long)b*N_*C_, fc1_b, (const bf16*)nullptr, f1b, 2*HF_, N_, 128, 3);
    dwconv_kernel<<<(HF_*N_ + 255)/256, 256, 0, stream>>>(f1b, dw_w, dw_b);
    gemm_kernel<float, bf16, false, float, float><<<dim3(49,2), 256, 0, stream>>>(
        fc2_w, f1b + (long)HF_*N_, fc2_b, x2 + (long)b*C_*N_,
        ((float*)d_out) + (long)b*C_*N_, C_, N_, HF_, 5);
  }
}

// Round 7
// 394.310 us; speedup vs baseline: 3.1266x; 1.2830x over previous
//
#include <hip/hip_runtime.h>
#include <hip/hip_bf16.h>

typedef __hip_bfloat16 bf16;
typedef short s8v __attribute__((ext_vector_type(8)));   // 8 bf16 = 4 VGPR MFMA frag
typedef float f4v __attribute__((ext_vector_type(4)));   // 4 fp32 MFMA acc

#define DEVI __device__ __forceinline__

DEVI float cvt(float x){ return x; }
DEVI float cvt(bf16 x){ return __bfloat162float(x); }

DEVI void stg(float* p, float v){ *p = v; }
DEVI void stg(bf16* p, float v){ *p = __float2bfloat16(v); }

DEVI float gelu_exact(float x){
  return 0.5f*x*(1.0f + erff(x*0.70710678118654752440f));
}

// problem constants
constexpr int B_ = 2, C_ = 128, H_ = 56, W_ = 56, N_ = 3136, NH_ = 4, D_ = 32, HF_ = 341;
constexpr int ROWS_ = B_*N_;             // 6272
constexpr int KF2 = 352;                 // fc2 K padded 341 -> 352 (11*32)

// ---------------- LayerNorm (one wave per row of 128 channels) ----------------
template<typename TX, typename TY, bool PLANES>
__global__ __launch_bounds__(256)
void ln_kernel(const TX* __restrict__ x, const float* __restrict__ w,
               const float* __restrict__ bia, TY* __restrict__ y)
{
  int gid = blockIdx.x*4 + (threadIdx.x>>6);      // row over B*N
  int lane = threadIdx.x & 63;
  int b = gid / N_, n = gid % N_;
  float v0, v1;
  if (PLANES){
    v0 = cvt(x[((long)b*C_ + lane     )*N_ + n]);
    v1 = cvt(x[((long)b*C_ + lane + 64)*N_ + n]);
  } else {
    v0 = cvt(x[(long)gid*C_ + lane     ]);
    v1 = cvt(x[(long)gid*C_ + lane + 64]);
  }
  float s = v0+v1, ss = v0*v0 + v1*v1;
  #pragma unroll
  for (int o=32;o>0;o>>=1){ s += __shfl_xor(s,o); ss += __shfl_xor(ss,o); }
  float mu  = s*(1.0f/128.0f);
  float var = fmaxf(ss*(1.0f/128.0f) - mu*mu, 0.f);
  float inv = rsqrtf(var + 1e-5f);
  stg(&y[(long)gid*C_ + lane     ], (v0-mu)*inv*w[lane     ] + bia[lane     ]);
  stg(&y[(long)gid*C_ + lane + 64], (v1-mu)*inv*w[lane + 64] + bia[lane + 64]);
}

// ---------------- weight fp32 -> bf16 conversion (fc2 K-padded to 352) ----------------
__global__ __launch_bounds__(256)
void convw_kernel(const float* __restrict__ q_w, const float* __restrict__ kv_w,
                  const float* __restrict__ sr_w, const float* __restrict__ proj_w,
                  const float* __restrict__ fc1_w, const float* __restrict__ fc2_w,
                  bf16* __restrict__ out)
{
  int t = blockIdx.x*256 + threadIdx.x;
  float v;
  if      (t <  16384) v = q_w[t];
  else if (t <  49152) v = kv_w[t-16384];
  else if (t <  65536) v = sr_w[t-49152];
  else if (t <  81920) v = proj_w[t-65536];
  else if (t < 169216) v = fc1_w[t-81920];
  else if (t < 214272){
    int i = t - 169216; int m = i / KF2, kp = i % KF2;
    v = (kp < HF_) ? fc2_w[m*HF_ + kp] : 0.f;
  } else return;
  out[t] = __float2bfloat16(v);
}

// ---------------- LDS-free MFMA GEMM ----------------
// out[m][n] = sum_k A[m][k] * B[n][k]; A,B bf16 k-contiguous rows (stride KT).
// Block 256 = 4 waves; tile 64(m) x 64(n); wave w does rows m0+w*16..+16.
// Frags straight from global (L2-resident). Verified layout (round 6):
// A-row = lane&15 (k at quad*8), B-row(n) = lane&15, D row=quad*4+r col=lane&15.
// MODE: 1=+bias[n] bf16; 2=+bias[n]+gelu bf16; 3=+bias[m] bf16;
//       4=+bias[n]+res fp32 out; 5=+bias[m]+res fp32 out.
template<int KT, int MODE, typename TC>
__global__ __launch_bounds__(256)
void gemm_mfma(const bf16* __restrict__ A, const bf16* __restrict__ B,
               const float* __restrict__ bias, const float* __restrict__ res,
               TC* __restrict__ Cm, int M, int Nn)
{
  int lane = threadIdx.x & 63, w = threadIdx.x >> 6;
  int m = lane & 15, quad = lane >> 4;
  int n0 = blockIdx.x*64, m0 = blockIdx.y*64;
  int arow = m0 + w*16 + m;
  if (arow >= M) arow = M-1;                    // clamp loads; stores guarded
  const bf16* ap = A + (long)arow*KT + quad*8;
  const bf16* bp = B + (long)(n0 + m)*KT + quad*8;
  f4v acc[4];
  #pragma unroll
  for (int s=0;s<4;s++) acc[s] = (f4v){0.f,0.f,0.f,0.f};
  #pragma unroll
  for (int k0 = 0; k0 < KT; k0 += 32){
    s8v af = *(const s8v*)(ap + k0);
    #pragma unroll
    for (int s=0;s<4;s++){
      s8v bf = *(const s8v*)(bp + (long)s*16*KT + k0);
      acc[s] = __builtin_amdgcn_mfma_f32_16x16x32_bf16(af, bf, acc[s], 0, 0, 0);
    }
  }
  #pragma unroll
  for (int s=0;s<4;s++){
    int gn = n0 + s*16 + m;
    #pragma unroll
    for (int r=0;r<4;r++){
      int gm = m0 + w*16 + quad*4 + r;
      if (gm >= M) continue;
      float v = acc[s][r];
      if (MODE==1 || MODE==2 || MODE==4) v += bias[gn];
      else                               v += bias[gm];
      if (MODE==2) v = gelu_exact(v);
      if (MODE>=4) v += res[(long)gm*Nn + gn];
      stg(&Cm[(long)gm*Nn + gn], v);
    }
  }
}

// ---------------- q post-process: l2n + embed + temperature -> qs ROWS ----------------
__global__ __launch_bounds__(256)
void post_q_kernel(const bf16* __restrict__ q_raw, const float* __restrict__ qe,
                   const float* __restrict__ temp, bf16* __restrict__ qs)
{
  int t = blockIdx.x*256 + threadIdx.x;        // (b*4+h)*N + n
  int n = t % N_; int bh = t / N_; int h = bh & 3; int b = bh >> 2;
  float sp = log1pf(expf(temp[h]));
  const bf16* qr = q_raw + ((long)(b*N_ + n))*C_ + h*D_;
  float v[32]; float ss = 0.f;
  #pragma unroll
  for (int d=0;d<32;d++){ v[d] = cvt(qr[d]); ss = fmaf(v[d], v[d], ss); }
  float inv = 1.f/fmaxf(sqrtf(ss), 1e-12f);
  bf16* qo = qs + ((long)bh*N_ + n)*D_;
  #pragma unroll
  for (int d=0;d<32;d++)
    stg(&qo[d], (v[d]*inv + qe[h*D_+d])*sp);
}

// ---------------- pooled kv post-process ----------------
// k_p: normalized key ROWS (bh, n, 32); v_p: value PLANES (bh, d, N)
__global__ __launch_bounds__(256)
void post_kvp_kernel(const bf16* __restrict__ kvp_raw,
                     bf16* __restrict__ kp, bf16* __restrict__ vp)
{
  int t = blockIdx.x*256 + threadIdx.x;        // bh*N + n
  int n = t % N_; int bh = t / N_; int h = bh & 3; int b = bh >> 2;
  const bf16* kr = kvp_raw + ((long)(b*N_ + n))*(2*C_) + h*D_;
  float v[32]; float ss = 0.f;
  #pragma unroll
  for (int d=0;d<32;d++){ v[d] = cvt(kr[d]); ss = fmaf(v[d], v[d], ss); }
  float inv = 1.f/fmaxf(sqrtf(ss), 1e-12f);
  bf16* ko = kp + ((long)bh*N_ + n)*D_;
  #pragma unroll
  for (int d=0;d<32;d++) stg(&ko[d], v[d]*inv);
  #pragma unroll
  for (int d=0;d<32;d++) vp[((long)bh*D_ + d)*N_ + n] = kr[C_ + d];
}

// ---------------- MFMA fused attention (round-6 verified; xo now bf16 rows) --------
__global__ __launch_bounds__(256)
void attn_mfma_kernel(const bf16* __restrict__ qs_, const bf16* __restrict__ kp_,
                      const bf16* __restrict__ vp_, const bf16* __restrict__ kv_,
                      const float* __restrict__ qe, const float* __restrict__ temp,
                      const float* __restrict__ tokens, const float* __restrict__ tbias,
                      bf16* __restrict__ xo)
{
  int bh = blockIdx.y; int h = bh & 3; int b = bh >> 2;
  int lane = threadIdx.x & 63;
  int w    = threadIdx.x >> 6;
  int m    = lane & 15, quad = lane >> 4;
  int q0   = blockIdx.x*64 + w*16;
  __shared__ float sm[4][608];                 // per-wave union: P 16x72 bf16 | O 16x36 f32 + L 16
  bf16*  Plds = (bf16*)sm[w];
  float* Olds = sm[w];

  s8v afrag = *(const s8v*)(qs_ + ((long)bh*N_ + q0 + m)*D_ + quad*8);
  const bf16* kpb = kp_ + (long)bh*N_*D_;
  const bf16* vpb = vp_ + (long)bh*D_*N_;
  f4v oacc0 = {0.f,0.f,0.f,0.f}, oacc1 = {0.f,0.f,0.f,0.f};
  float lacc[4] = {0.f,0.f,0.f,0.f};

  for (int t0 = 0; t0 < N_; t0 += 64){
    float p[4][4];
    #pragma unroll
    for (int s = 0; s < 4; s++){
      s8v bfrag = *(const s8v*)(kpb + (long)(t0 + s*16 + m)*D_ + quad*8);
      f4v c = {0.f,0.f,0.f,0.f};
      c = __builtin_amdgcn_mfma_f32_16x16x32_bf16(afrag, bfrag, c, 0, 0, 0);
      #pragma unroll
      for (int r=0;r<4;r++){
        float e = __expf(c[r] - 8.f);          // D: row=quad*4+r (query), col=m (key)
        lacc[r] += e;
        p[s][r] = e;
      }
    }
    #pragma unroll
    for (int s=0;s<4;s++)
      #pragma unroll
      for (int r=0;r<4;r++)
        Plds[(quad*4+r)*72 + s*16 + m] = __float2bfloat16(p[s][r]);
    #pragma unroll
    for (int c2=0;c2<2;c2++){
      s8v pa  = *(const s8v*)(Plds + m*72 + c2*32 + quad*8);
      s8v vb0 = *(const s8v*)(vpb + (long)(m     )*N_ + t0 + c2*32 + quad*8);
      s8v vb1 = *(const s8v*)(vpb + (long)(16 + m)*N_ + t0 + c2*32 + quad*8);
      oacc0 = __builtin_amdgcn_mfma_f32_16x16x32_bf16(pa, vb0, oacc0, 0, 0, 0);
      oacc1 = __builtin_amdgcn_mfma_f32_16x16x32_bf16(pa, vb1, oacc1, 0, 0, 0);
    }
  }
  #pragma unroll
  for (int off=1; off<16; off<<=1)
    #pragma unroll
    for (int r=0;r<4;r++) lacc[r] += __shfl_xor(lacc[r], off);
  #pragma unroll
  for (int r=0;r<4;r++){
    Olds[(quad*4+r)*36 + m     ] = oacc0[r];
    Olds[(quad*4+r)*36 + 16 + m] = oacc1[r];
  }
  if (m == 0){
    #pragma unroll
    for (int r=0;r<4;r++) Olds[576 + quad*4 + r] = lacc[r];
  }
  // ---- epilogue: lane -> (query m, dim-group quad) ----
  int nq = q0 + m;
  int dg = quad;
  f4v ov0 = *(const f4v*)(Olds + m*36 + dg*8);
  f4v ov1 = *(const f4v*)(Olds + m*36 + dg*8 + 4);
  float Lp = Olds[576 + m];
  float sp = log1pf(expf(temp[h]));
  float invsp = 1.f/sp;
  float q8[8], qn8[8];
  const bf16* qrow8 = qs_ + ((long)bh*N_ + nq)*D_ + dg*8;
  #pragma unroll
  for (int j=0;j<8;j++){
    q8[j]  = cvt(qrow8[j]);
    qn8[j] = q8[j]*invsp - qe[h*D_ + dg*8 + j];
  }
  int hy = nq / W_, wx = nq % W_;
  float Ltot = Lp;
  float sl[9], tk[9];
  #pragma unroll
  for (int k=0;k<9;k++){
    int di = k/3-1, dj = k%3-1;
    int yy = hy+di, xx = wx+dj;
    bool inb = (yy>=0 && yy<H_ && xx>=0 && xx<W_);
    float dotp = 0.f, ssp = 0.f, tokp = 0.f;
    if (inb){
      const bf16* kr = kv_ + (long)b*N_*(2*C_) + (long)(yy*W_+xx)*(2*C_) + h*D_ + dg*8;
      #pragma unroll
      for (int j=0;j<8;j++){
        float kk = cvt(kr[j]);
        dotp = fmaf(q8[j], kk, dotp);
        ssp  = fmaf(kk, kk, ssp);
      }
    }
    #pragma unroll
    for (int j=0;j<8;j++) tokp = fmaf(qn8[j], tokens[(h*D_ + dg*8 + j)*9 + k], tokp);
    dotp += __shfl_xor(dotp,16); dotp += __shfl_xor(dotp,32);
    ssp  += __shfl_xor(ssp ,16); ssp  += __shfl_xor(ssp ,32);
    tokp += __shfl_xor(tokp,16); tokp += __shfl_xor(tokp,32);
    float s = dotp / fmaxf(sqrtf(ssp), 1e-12f);   // OOB: 0 (zero-padded key)
    sl[k] = s; tk[k] = tokp;
    Ltot += __expf(s - 8.f);
  }
  float invL = 1.f/Ltot;
  float out8[8];
  #pragma unroll
  for (int j=0;j<4;j++){ out8[j] = ov0[j]*invL; out8[4+j] = ov1[j]*invL; }
  #pragma unroll
  for (int k=0;k<9;k++){
    int di = k/3-1, dj = k%3-1;
    int yy = hy+di, xx = wx+dj;
    float wl = tk[k] + tbias[h*9+k] + __expf(sl[k] - 8.f)*invL;
    if (yy>=0 && yy<H_ && xx>=0 && xx<W_){
      const bf16* vr = kv_ + (long)b*N_*(2*C_) + (long)(yy*W_+xx)*(2*C_) + C_ + h*D_ + dg*8;
      #pragma unroll
      for (int j=0;j<8;j++) out8[j] = fmaf(wl, cvt(vr[j]), out8[j]);
    }
  }
  bf16 o8[8];
  #pragma unroll
  for (int j=0;j<8;j++) o8[j] = __float2bfloat16(out8[j]);
  *(s8v*)(xo + ((long)(b*N_ + nq))*C_ + h*D_ + dg*8) = *(const s8v*)o8;
}

// ---------------- depthwise 3x3 + bias + gelu, gated -> g ROWS (n, 352) ----------------
// one batch. thread -> (n, cg): 8 channels c0=cg*8..+8; writes 16B row chunk.
// c >= 341 (and cg=42 tail, cg=43) write zeros -> zero-padded K for fc2 MFMA.
__global__ __launch_bounds__(256)
void dwconv_kernel(const bf16* __restrict__ f1, const float* __restrict__ dww,
                   const float* __restrict__ dwb, bf16* __restrict__ g)
{
  int t = blockIdx.x*256 + threadIdx.x;
  if (t >= N_*44) return;
  int cg = t % 44, n = t / 44;
  int c0 = cg*8;
  int hy = n / W_, wx = n % W_;
  bf16 o8[8];
  #pragma unroll
  for (int j=0;j<8;j++){
    int c = c0 + j;
    float val = 0.f;
    if (c < HF_){
      const bf16* ap = f1 + (long)c*N_;
      float s = dwb[c];
      #pragma unroll
      for (int di=-1; di<=1; di++)
        #pragma unroll
        for (int dj=-1; dj<=1; dj++){
          int yy = hy+di, xx = wx+dj;
          if (yy>=0 && yy<H_ && xx>=0 && xx<W_)
            s = fmaf(dww[c*9 + (di+1)*3 + (dj+1)], cvt(ap[yy*W_+xx]), s);
        }
      val = gelu_exact(s) * cvt(f1[(long)(HF_+c)*N_ + n]);
    }
    o8[j] = __float2bfloat16(val);
  }
  *(s8v*)(g + (long)n*KF2 + c0) = *(const s8v*)o8;
}

// ---------------- launcher ----------------
extern "C" void kernel_launch(void* const* d_in, const int* in_sizes, int n_in,
                              void* d_out, int out_size, void* d_ws, size_t ws_size,
                              hipStream_t stream)
{
  (void)in_sizes; (void)n_in; (void)out_size; (void)ws_size;
  const float* x_in      = (const float*)d_in[0];
  const float* norm1_w   = (const float*)d_in[1];
  const float* norm1_b   = (const float*)d_in[2];
  const float* q_w       = (const float*)d_in[3];
  const float* q_b       = (const float*)d_in[4];
  const float* kv_w      = (const float*)d_in[5];
  const float* kv_b      = (const float*)d_in[6];
  const float* temp      = (const float*)d_in[7];
  const float* qe        = (const float*)d_in[8];
  const float* tokens    = (const float*)d_in[9];
  const float* tbias     = (const float*)d_in[10];
  const float* sr_w      = (const float*)d_in[11];
  const float* sr_b      = (const float*)d_in[12];
  const float* pln_w     = (const float*)d_in[13];
  const float* pln_b     = (const float*)d_in[14];
  const float* proj_w    = (const float*)d_in[15];
  const float* proj_b    = (const float*)d_in[16];
  const float* norm2_w   = (const float*)d_in[17];
  const float* norm2_b   = (const float*)d_in[18];
  const float* fc1_w     = (const float*)d_in[19];
  const float* fc1_b     = (const float*)d_in[20];
  const float* dw_w      = (const float*)d_in[21];
  const float* dw_b      = (const float*)d_in[22];
  const float* fc2_w     = (const float*)d_in[23];
  const float* fc2_b     = (const float*)d_in[24];

  // ---- workspace plan (bytes), peak 11,730,688 (11.2 MiB) ----
  // A [0,3211264):         kv_raw bf16 rows (B,N,2C) -> x2 fp32 flat after attn
  // B [3211264,6422528):   kvp_raw bf16 rows         \_ f1b bf16 planes (682,N)
  // C [6422528,8028160):   qs bf16 rows (bh,N,32)    /  [3211264,7488768)
  // D [8028160,9633792):   y -> xp -> k_p rows
  // E [9633792,11239424):  q_raw -> xp_raw -> v_p planes
  // y2 [7488768,9094400):  bf16 rows (after attn; overlaps C tail + D head, both dead)
  // g  [9094400,11302144): g rows (N,352) bf16 per batch (overlaps E, dead)
  // W  [11302144,11730688): bf16 weights (q,kv,sr,proj,fc1,fc2-padded)
  // xo: d_out used as bf16 rows scratch; fully overwritten (fp32) by fc2 b0/b1.
  char* w8 = (char*)d_ws;
  bf16*  kv_raw  = (bf16*)(w8 + 0);
  float* x2      = (float*)(w8 + 0);
  bf16*  kvp_raw = (bf16*)(w8 + 3211264);
  bf16*  f1b     = (bf16*)(w8 + 3211264);
  bf16*  qs      = (bf16*)(w8 + 6422528);
  bf16*  y       = (bf16*)(w8 + 8028160);
  bf16*  q_raw   = (bf16*)(w8 + 9633792);
  bf16*  y2      = (bf16*)(w8 + 7488768);
  bf16*  g_rows  = (bf16*)(w8 + 9094400);
  bf16*  wbase   = (bf16*)(w8 + 11302144);
  bf16*  xp_raw  = q_raw;
  bf16*  xp      = y;
  bf16*  k_p     = y;
  bf16*  v_p     = q_raw;
  bf16*  xo      = (bf16*)d_out;
  bf16*  q_wb    = wbase;
  bf16*  kv_wb   = wbase + 16384;
  bf16*  sr_wb   = wbase + 49152;
  bf16*  proj_wb = wbase + 65536;
  bf16*  fc1_wb  = wbase + 81920;
  bf16*  fc2_wb  = wbase + 169216;

  // 0. weights -> bf16 (fc2 K-padded)
  convw_kernel<<<(214272+255)/256, 256, 0, stream>>>(q_w, kv_w, sr_w, proj_w, fc1_w, fc2_w, wbase);
  // 1. y = LN1(x)
  ln_kernel<float, bf16, true><<<ROWS_/4, 256, 0, stream>>>(x_in, norm1_w, norm1_b, y);
  // 2. q_raw = y @ q_w^T + q_b
  gemm_mfma<128, 1, bf16><<<dim3(2,98), 256, 0, stream>>>(y, q_wb, q_b, nullptr, q_raw, ROWS_, 128);
  // 3. kv_raw = y @ kv_w^T + kv_b
  gemm_mfma<128, 1, bf16><<<dim3(4,98), 256, 0, stream>>>(y, kv_wb, kv_b, nullptr, kv_raw, ROWS_, 256);
  // 4. qs rows
  post_q_kernel<<<98, 256, 0, stream>>>(q_raw, qe, temp, qs);
  // 5. xp_raw = gelu(y @ sr_w^T + sr_b)
  gemm_mfma<128, 2, bf16><<<dim3(2,98), 256, 0, stream>>>(y, sr_wb, sr_b, nullptr, xp_raw, ROWS_, 128);
  // 6. xp = LN_pln(xp_raw)
  ln_kernel<bf16, bf16, false><<<ROWS_/4, 256, 0, stream>>>(xp_raw, pln_w, pln_b, xp);
  // 7. kvp_raw = xp @ kv_w^T + kv_b
  gemm_mfma<128, 1, bf16><<<dim3(4,98), 256, 0, stream>>>(xp, kv_wb, kv_b, nullptr, kvp_raw, ROWS_, 256);
  // 7.5 k_p rows + v_p planes
  post_kvp_kernel<<<98, 256, 0, stream>>>(kvp_raw, k_p, v_p);
  // 8. MFMA fused attention -> xo (bf16 rows in d_out scratch)
  attn_mfma_kernel<<<dim3(49,8), 256, 0, stream>>>(qs, k_p, v_p, kv_raw, qe, temp, tokens, tbias, xo);
  // 9. x2 = x_in + (xo @ proj_w^T + proj_b)   (flat-reinterpret residual)
  gemm_mfma<128, 4, float><<<dim3(2,98), 256, 0, stream>>>(xo, proj_wb, proj_b, x_in, x2, ROWS_, 128);
  // 10. y2 = LN2(x2)
  ln_kernel<float, bf16, true><<<ROWS_/4, 256, 0, stream>>>(x2, norm2_w, norm2_b, y2);
  // 11. MLP per batch
  for (int b = 0; b < B_; b++){
    // f1b = fc1_w @ y2_b^T + fc1_b  -> bf16 planes (682, N)
    gemm_mfma<128, 3, bf16><<<dim3(49,11), 256, 0, stream>>>(
        fc1_wb, y2 + (long)b*N_*C_, fc1_b, nullptr, f1b, 2*HF_, N_);
    // g rows = gelu(dw(a)+dw_b) * v, K-padded to 352
    dwconv_kernel<<<(N_*44+255)/256, 256, 0, stream>>>(f1b, dw_w, dw_b, g_rows);
    // out_b = x2_b + fc2_w @ g + fc2_b  (fp32 out to d_out)
    gemm_mfma<KF2, 5, float><<<dim3(49,2), 256, 0, stream>>>(
        fc2_wb, g_rows, fc2_b, x2 + (long)b*C_*N_,
        ((float*)d_out) + (long)b*C_*N_, C_, N_);
  }
}

// Round 10
// 343.424 us; speedup vs baseline: 3.5899x; 1.1482x over previous
//
#include <hip/hip_runtime.h>
#include <hip/hip_bf16.h>

typedef __hip_bfloat16 bf16;
typedef short s8v __attribute__((ext_vector_type(8)));   // 8 bf16 = 4 VGPR MFMA frag
typedef float f4v __attribute__((ext_vector_type(4)));   // 4 fp32 MFMA acc

#define DEVI __device__ __forceinline__

DEVI float cvt(float x){ return x; }
DEVI float cvt(bf16 x){ return __bfloat162float(x); }

DEVI void stg(float* p, float v){ *p = v; }
DEVI void stg(bf16* p, float v){ *p = __float2bfloat16(v); }

DEVI float gelu_exact(float x){
  return 0.5f*x*(1.0f + erff(x*0.70710678118654752440f));
}

// problem constants
constexpr int B_ = 2, C_ = 128, H_ = 56, W_ = 56, N_ = 3136, NH_ = 4, D_ = 32, HF_ = 341;
constexpr int ROWS_ = B_*N_;             // 6272
constexpr int KF2 = 352;                 // fc2 K padded 341 -> 352 (11*32)
constexpr int GQ_ = NH_*B_*N_;           // 25088 (bh*N + n)

// ---------------- LayerNorm (one wave per row of 128 channels) ----------------
template<typename TX, typename TY, bool PLANES>
__global__ __launch_bounds__(256)
void ln_kernel(const TX* __restrict__ x, const float* __restrict__ w,
               const float* __restrict__ bia, TY* __restrict__ y)
{
  int gid = blockIdx.x*4 + (threadIdx.x>>6);      // row over B*N
  int lane = threadIdx.x & 63;
  int b = gid / N_, n = gid % N_;
  float v0, v1;
  if (PLANES){
    v0 = cvt(x[((long)b*C_ + lane     )*N_ + n]);
    v1 = cvt(x[((long)b*C_ + lane + 64)*N_ + n]);
  } else {
    v0 = cvt(x[(long)gid*C_ + lane     ]);
    v1 = cvt(x[(long)gid*C_ + lane + 64]);
  }
  float s = v0+v1, ss = v0*v0 + v1*v1;
  #pragma unroll
  for (int o=32;o>0;o>>=1){ s += __shfl_xor(s,o); ss += __shfl_xor(ss,o); }
  float mu  = s*(1.0f/128.0f);
  float var = fmaxf(ss*(1.0f/128.0f) - mu*mu, 0.f);
  float inv = rsqrtf(var + 1e-5f);
  stg(&y[(long)gid*C_ + lane     ], (v0-mu)*inv*w[lane     ] + bia[lane     ]);
  stg(&y[(long)gid*C_ + lane + 64], (v1-mu)*inv*w[lane + 64] + bia[lane + 64]);
}

// ---------------- weight fp32 -> bf16 conversion (fc2 K-padded to 352) ----------------
__global__ __launch_bounds__(256)
void convw_kernel(const float* __restrict__ q_w, const float* __restrict__ kv_w,
                  const float* __restrict__ sr_w, const float* __restrict__ proj_w,
                  const float* __restrict__ fc1_w, const float* __restrict__ fc2_w,
                  bf16* __restrict__ out)
{
  int t = blockIdx.x*256 + threadIdx.x;
  float v;
  if      (t <  16384) v = q_w[t];
  else if (t <  49152) v = kv_w[t-16384];
  else if (t <  65536) v = sr_w[t-49152];
  else if (t <  81920) v = proj_w[t-65536];
  else if (t < 169216) v = fc1_w[t-81920];
  else if (t < 214272){
    int i = t - 169216; int m = i / KF2, kp = i % KF2;
    v = (kp < HF_) ? fc2_w[m*HF_ + kp] : 0.f;
  } else return;
  out[t] = __float2bfloat16(v);
}

// ---------------- LDS-free MFMA GEMM (round-7 verified) ----------------
template<int KT, int MODE, typename TC>
__global__ __launch_bounds__(256)
void gemm_mfma(const bf16* __restrict__ A, const bf16* __restrict__ B,
               const float* __restrict__ bias, const float* __restrict__ res,
               TC* __restrict__ Cm, int M, int Nn)
{
  int lane = threadIdx.x & 63, w = threadIdx.x >> 6;
  int m = lane & 15, quad = lane >> 4;
  int n0 = blockIdx.x*64, m0 = blockIdx.y*64;
  int arow = m0 + w*16 + m;
  if (arow >= M) arow = M-1;                    // clamp loads; stores guarded
  const bf16* ap = A + (long)arow*KT + quad*8;
  const bf16* bp = B + (long)(n0 + m)*KT + quad*8;
  f4v acc[4];
  #pragma unroll
  for (int s=0;s<4;s++) acc[s] = (f4v){0.f,0.f,0.f,0.f};
  #pragma unroll
  for (int k0 = 0; k0 < KT; k0 += 32){
    s8v af = *(const s8v*)(ap + k0);
    #pragma unroll
    for (int s=0;s<4;s++){
      s8v bf = *(const s8v*)(bp + (long)s*16*KT + k0);
      acc[s] = __builtin_amdgcn_mfma_f32_16x16x32_bf16(af, bf, acc[s], 0, 0, 0);
    }
  }
  #pragma unroll
  for (int s=0;s<4;s++){
    int gn = n0 + s*16 + m;
    #pragma unroll
    for (int r=0;r<4;r++){
      int gm = m0 + w*16 + quad*4 + r;
      if (gm >= M) continue;
      float v = acc[s][r];
      if (MODE==1 || MODE==2 || MODE==4) v += bias[gn];
      else                               v += bias[gm];
      if (MODE==2) v = gelu_exact(v);
      if (MODE>=4) v += res[(long)gm*Nn + gn];
      stg(&Cm[(long)gm*Nn + gn], v);
    }
  }
}

// ---------------- q post-process: l2n + embed + temperature -> qs ROWS ----------------
__global__ __launch_bounds__(256)
void post_q_kernel(const bf16* __restrict__ q_raw, const float* __restrict__ qe,
                   const float* __restrict__ temp, bf16* __restrict__ qs)
{
  int t = blockIdx.x*256 + threadIdx.x;        // (b*4+h)*N + n
  int n = t % N_; int bh = t / N_; int h = bh & 3; int b = bh >> 2;
  float sp = log1pf(expf(temp[h]));
  const bf16* qr = q_raw + ((long)(b*N_ + n))*C_ + h*D_;
  float v[32]; float ss = 0.f;
  #pragma unroll
  for (int d=0;d<32;d++){ v[d] = cvt(qr[d]); ss = fmaf(v[d], v[d], ss); }
  float inv = 1.f/fmaxf(sqrtf(ss), 1e-12f);
  bf16* qo = qs + ((long)bh*N_ + n)*D_;
  #pragma unroll
  for (int d=0;d<32;d++)
    stg(&qo[d], (v[d]*inv + qe[h*D_+d])*sp);
}

// ---------------- pooled kv post-process ----------------
__global__ __launch_bounds__(256)
void post_kvp_kernel(const bf16* __restrict__ kvp_raw,
                     bf16* __restrict__ kp, bf16* __restrict__ vp)
{
  int t = blockIdx.x*256 + threadIdx.x;        // bh*N + n
  int n = t % N_; int bh = t / N_; int h = bh & 3; int b = bh >> 2;
  const bf16* kr = kvp_raw + ((long)(b*N_ + n))*(2*C_) + h*D_;
  float v[32]; float ss = 0.f;
  #pragma unroll
  for (int d=0;d<32;d++){ v[d] = cvt(kr[d]); ss = fmaf(v[d], v[d], ss); }
  float inv = 1.f/fmaxf(sqrtf(ss), 1e-12f);
  bf16* ko = kp + ((long)bh*N_ + n)*D_;
  #pragma unroll
  for (int d=0;d<32;d++) stg(&ko[d], v[d]*inv);
  #pragma unroll
  for (int d=0;d<32;d++) vp[((long)bh*D_ + d)*N_ + n] = kr[C_ + d];
}

// ---------------- MFMA pool-attention PARTIAL (2-way key split) ----------------
// grid (49, 8, 2); block 256 = 4 waves; wave owns 16 queries; split z covers keys
// z*1600 .. min(+1600, N). Writes unnormalized O partial (bf16) + L partial (fp32).
__global__ __launch_bounds__(256)
void attn_part_kernel(const bf16* __restrict__ qs_, const bf16* __restrict__ kp_,
                      const bf16* __restrict__ vp_,
                      bf16* __restrict__ Op, float* __restrict__ Lp)
{
  int bh = blockIdx.y;
  int z  = blockIdx.z;
  int lane = threadIdx.x & 63;
  int w    = threadIdx.x >> 6;
  int m    = lane & 15, quad = lane >> 4;
  int q0   = blockIdx.x*64 + w*16;
  __shared__ float sm[4][608];                 // per-wave: P 16x72 bf16 | O 16x36 f32 + L 16
  bf16*  Plds = (bf16*)sm[w];
  float* Olds = sm[w];

  s8v afrag = *(const s8v*)(qs_ + ((long)bh*N_ + q0 + m)*D_ + quad*8);
  const bf16* kpb = kp_ + (long)bh*N_*D_;
  const bf16* vpb = vp_ + (long)bh*D_*N_;
  f4v oacc0 = {0.f,0.f,0.f,0.f}, oacc1 = {0.f,0.f,0.f,0.f};
  float lacc[4] = {0.f,0.f,0.f,0.f};

  int tlo = z*1600, thi = min(tlo + 1600, N_);
  for (int t0 = tlo; t0 < thi; t0 += 64){
    float p[4][4];
    #pragma unroll
    for (int s = 0; s < 4; s++){
      s8v bfrag = *(const s8v*)(kpb + (long)(t0 + s*16 + m)*D_ + quad*8);
      f4v c = {0.f,0.f,0.f,0.f};
      c = __builtin_amdgcn_mfma_f32_16x16x32_bf16(afrag, bfrag, c, 0, 0, 0);
      #pragma unroll
      for (int r=0;r<4;r++){
        float e = __expf(c[r] - 8.f);          // D: row=quad*4+r (query), col=m (key)
        lacc[r] += e;
        p[s][r] = e;
      }
    }
    #pragma unroll
    for (int s=0;s<4;s++)
      #pragma unroll
      for (int r=0;r<4;r++)
        Plds[(quad*4+r)*72 + s*16 + m] = __float2bfloat16(p[s][r]);
    #pragma unroll
    for (int c2=0;c2<2;c2++){
      s8v pa  = *(const s8v*)(Plds + m*72 + c2*32 + quad*8);
      s8v vb0 = *(const s8v*)(vpb + (long)(m     )*N_ + t0 + c2*32 + quad*8);
      s8v vb1 = *(const s8v*)(vpb + (long)(16 + m)*N_ + t0 + c2*32 + quad*8);
      oacc0 = __builtin_amdgcn_mfma_f32_16x16x32_bf16(pa, vb0, oacc0, 0, 0, 0);
      oacc1 = __builtin_amdgcn_mfma_f32_16x16x32_bf16(pa, vb1, oacc1, 0, 0, 0);
    }
  }
  #pragma unroll
  for (int off=1; off<16; off<<=1)
    #pragma unroll
    for (int r=0;r<4;r++) lacc[r] += __shfl_xor(lacc[r], off);
  #pragma unroll
  for (int r=0;r<4;r++){
    Olds[(quad*4+r)*36 + m     ] = oacc0[r];
    Olds[(quad*4+r)*36 + 16 + m] = oacc1[r];
  }
  if (m == 0){
    #pragma unroll
    for (int r=0;r<4;r++) Olds[576 + quad*4 + r] = lacc[r];
  }
  // lane remap: query = m, dim-group = quad; coalesced 16B partial store
  long gq = (long)bh*N_ + q0 + m;
  f4v ov0 = *(const f4v*)(Olds + m*36 + quad*8);
  f4v ov1 = *(const f4v*)(Olds + m*36 + quad*8 + 4);
  bf16 o8[8];
  #pragma unroll
  for (int j=0;j<4;j++){ o8[j] = __float2bfloat16(ov0[j]); o8[4+j] = __float2bfloat16(ov1[j]); }
  *(s8v*)(Op + ((long)z*GQ_ + gq)*32 + quad*8) = *(const s8v*)o8;
  if (quad == 0) Lp[(long)z*GQ_ + gq] = Olds[576 + m];
}

// ---------------- combine partials + local 3x3 + learnable tokens -> xo rows --------
__global__ __launch_bounds__(256)
void attn_combine_kernel(const bf16* __restrict__ Op, const float* __restrict__ Lp,
                         const bf16* __restrict__ qs_, const bf16* __restrict__ kv_,
                         const float* __restrict__ qe, const float* __restrict__ temp,
                         const float* __restrict__ tokens, const float* __restrict__ tbias,
                         bf16* __restrict__ xo)
{
  int gq = blockIdx.x*256 + threadIdx.x;       // bh*N + n, 25088 total
  int n = gq % N_; int bh = gq / N_; int h = bh & 3; int b = bh >> 2;
  float L = Lp[gq] + Lp[GQ_ + gq];
  const bf16* o0 = Op + (long)gq*32;
  const bf16* o1 = Op + ((long)GQ_ + gq)*32;
  float out[32];
  #pragma unroll
  for (int d=0;d<32;d++) out[d] = cvt(o0[d]) + cvt(o1[d]);
  const bf16* qrow = qs_ + (long)gq*D_;
  float q[32];
  #pragma unroll
  for (int d=0;d<32;d++) q[d] = cvt(qrow[d]);
  // local 3x3: keys/values from kv_raw rows, keys normalized inline.
  int hy = n / W_, wx = n % W_;
  const bf16* kvb = kv_ + (long)b*N_*(2*C_) + h*D_;
  float sl[9];
  #pragma unroll
  for (int k=0;k<9;k++){
    int di = k/3-1, dj = k%3-1;
    int yy = hy+di, xx = wx+dj;
    float s = 0.f;
    if (yy>=0 && yy<H_ && xx>=0 && xx<W_){
      long nn2 = (long)(yy*W_+xx)*(2*C_);
      float dot = 0.f, ss = 0.f;
      #pragma unroll
      for (int d=0;d<32;d++){
        float kk = cvt(kvb[nn2 + d]);
        dot = fmaf(q[d], kk, dot);
        ss  = fmaf(kk, kk, ss);
      }
      s = dot / fmaxf(sqrtf(ss), 1e-12f);
    }
    sl[k] = s;                                  // OOB: exactly 0 (zero-padded key)
  }
  #pragma unroll
  for (int k=0;k<9;k++) L += __expf(sl[k] - 8.f);
  float invL = 1.f/L;
  #pragma unroll
  for (int d=0;d<32;d++) out[d] *= invL;
  float sp = log1pf(expf(temp[h]));
  float invsp = 1.f/sp;
  float qn[32];
  #pragma unroll
  for (int d=0;d<32;d++) qn[d] = q[d]*invsp - qe[h*D_+d];
  #pragma unroll
  for (int k=0;k<9;k++){
    float tok = 0.f;
    #pragma unroll
    for (int d=0;d<32;d++) tok = fmaf(qn[d], tokens[(h*D_+d)*9+k], tok);
    float wl = tok + tbias[h*9+k] + __expf(sl[k] - 8.f)*invL;
    int di = k/3-1, dj = k%3-1;
    int yy = hy+di, xx = wx+dj;
    if (yy>=0 && yy<H_ && xx>=0 && xx<W_){      // OOB v_l zero-padded -> contributes 0
      long nn2 = (long)(yy*W_+xx)*(2*C_);
      #pragma unroll
      for (int d=0;d<32;d++) out[d] = fmaf(wl, cvt(kvb[nn2 + C_ + d]), out[d]);
    }
  }
  bf16* op = xo + ((long)(b*N_ + n))*C_ + h*D_;
  #pragma unroll
  for (int d=0;d<32;d++) stg(&op[d], out[d]);
}

// ---------------- depthwise 3x3 + bias + gelu, gated -> g ROWS (n, 352) ----------------
// COALESCED mapping: n fastest (consecutive lanes -> consecutive n); cg wave-uniform.
__global__ __launch_bounds__(256)
void dwconv_kernel(const bf16* __restrict__ f1, const float* __restrict__ dww,
                   const float* __restrict__ dwb, bf16* __restrict__ g)
{
  int t = blockIdx.x*256 + threadIdx.x;
  if (t >= N_*44) return;
  int n = t % N_, cg = t / N_;
  int c0 = cg*8;
  int hy = n / W_, wx = n % W_;
  bf16 o8[8];
  #pragma unroll
  for (int j=0;j<8;j++){
    int c = c0 + j;
    float val = 0.f;
    if (c < HF_){
      const bf16* ap = f1 + (long)c*N_;
      float s = dwb[c];
      #pragma unroll
      for (int di=-1; di<=1; di++)
        #pragma unroll
        for (int dj=-1; dj<=1; dj++){
          int yy = hy+di, xx = wx+dj;
          if (yy>=0 && yy<H_ && xx>=0 && xx<W_)
            s = fmaf(dww[c*9 + (di+1)*3 + (dj+1)], cvt(ap[yy*W_+xx]), s);
        }
      val = gelu_exact(s) * cvt(f1[(long)(HF_+c)*N_ + n]);
    }
    o8[j] = __float2bfloat16(val);
  }
  *(s8v*)(g + (long)n*KF2 + c0) = *(const s8v*)o8;
}

// ---------------- launcher ----------------
extern "C" void kernel_launch(void* const* d_in, const int* in_sizes, int n_in,
                              void* d_out, int out_size, void* d_ws, size_t ws_size,
                              hipStream_t stream)
{
  (void)in_sizes; (void)n_in; (void)out_size; (void)ws_size;
  const float* x_in      = (const float*)d_in[0];
  const float* norm1_w   = (const float*)d_in[1];
  const float* norm1_b   = (const float*)d_in[2];
  const float* q_w       = (const float*)d_in[3];
  const float* q_b       = (const float*)d_in[4];
  const float* kv_w      = (const float*)d_in[5];
  const float* kv_b      = (const float*)d_in[6];
  const float* temp      = (const float*)d_in[7];
  const float* qe        = (const float*)d_in[8];
  const float* tokens    = (const float*)d_in[9];
  const float* tbias     = (const float*)d_in[10];
  const float* sr_w      = (const float*)d_in[11];
  const float* sr_b      = (const float*)d_in[12];
  const float* pln_w     = (const float*)d_in[13];
  const float* pln_b     = (const float*)d_in[14];
  const float* proj_w    = (const float*)d_in[15];
  const float* proj_b    = (const float*)d_in[16];
  const float* norm2_w   = (const float*)d_in[17];
  const float* norm2_b   = (const float*)d_in[18];
  const float* fc1_w     = (const float*)d_in[19];
  const float* fc1_b     = (const float*)d_in[20];
  const float* dw_w      = (const float*)d_in[21];
  const float* dw_b      = (const float*)d_in[22];
  const float* fc2_w     = (const float*)d_in[23];
  const float* fc2_b     = (const float*)d_in[24];

  // ---- workspace plan (bytes), peak 11,730,688 (same as round 7, proven) ----
  // A [0,3211264):         kv_raw bf16 rows -> x2 fp32 flat (after combine)
  // B [3211264,6422528):   kvp_raw bf16 rows -> O partials (2 x 25088 x 32 bf16, EXACT fit)
  //                        -> f1b bf16 planes [3211264,7488768) per batch (MLP)
  // C [6422528,8028160):   qs bf16 rows (alive through combine)
  // D [8028160,9633792):   y -> xp -> k_p rows -> y2 [7488768,9094400)
  // E [9633792,11239424):  q_raw -> xp_raw -> v_p planes
  // g  [9094400,11302144): g rows (N,352) per batch
  // W  [11302144,11730688): bf16 weights
  // d_out: xo bf16 rows [0,1605632) + L partials fp32 [1605632,1806336);
  //        fully overwritten (fp32) by fc2 at the end.
  char* w8 = (char*)d_ws;
  bf16*  kv_raw  = (bf16*)(w8 + 0);
  float* x2      = (float*)(w8 + 0);
  bf16*  kvp_raw = (bf16*)(w8 + 3211264);
  bf16*  Opart   = (bf16*)(w8 + 3211264);
  bf16*  f1b     = (bf16*)(w8 + 3211264);
  bf16*  qs      = (bf16*)(w8 + 6422528);
  bf16*  y       = (bf16*)(w8 + 8028160);
  bf16*  q_raw   = (bf16*)(w8 + 9633792);
  bf16*  y2      = (bf16*)(w8 + 7488768);
  bf16*  g_rows  = (bf16*)(w8 + 9094400);
  bf16*  wbase   = (bf16*)(w8 + 11302144);
  bf16*  xp_raw  = q_raw;
  bf16*  xp      = y;
  bf16*  k_p     = y;
  bf16*  v_p     = q_raw;
  bf16*  xo      = (bf16*)d_out;
  float* Lpart   = (float*)((char*)d_out + 1605632);
  bf16*  q_wb    = wbase;
  bf16*  kv_wb   = wbase + 16384;
  bf16*  sr_wb   = wbase + 49152;
  bf16*  proj_wb = wbase + 65536;
  bf16*  fc1_wb  = wbase + 81920;
  bf16*  fc2_wb  = wbase + 169216;

  // 0. weights -> bf16 (fc2 K-padded)
  convw_kernel<<<(214272+255)/256, 256, 0, stream>>>(q_w, kv_w, sr_w, proj_w, fc1_w, fc2_w, wbase);
  // 1. y = LN1(x)
  ln_kernel<float, bf16, true><<<ROWS_/4, 256, 0, stream>>>(x_in, norm1_w, norm1_b, y);
  // 2. q_raw = y @ q_w^T + q_b
  gemm_mfma<128, 1, bf16><<<dim3(2,98), 256, 0, stream>>>(y, q_wb, q_b, nullptr, q_raw, ROWS_, 128);
  // 3. kv_raw = y @ kv_w^T + kv_b
  gemm_mfma<128, 1, bf16><<<dim3(4,98), 256, 0, stream>>>(y, kv_wb, kv_b, nullptr, kv_raw, ROWS_, 256);
  // 4. qs rows
  post_q_kernel<<<98, 256, 0, stream>>>(q_raw, qe, temp, qs);
  // 5. xp_raw = gelu(y @ sr_w^T + sr_b)
  gemm_mfma<128, 2, bf16><<<dim3(2,98), 256, 0, stream>>>(y, sr_wb, sr_b, nullptr, xp_raw, ROWS_, 128);
  // 6. xp = LN_pln(xp_raw)
  ln_kernel<bf16, bf16, false><<<ROWS_/4, 256, 0, stream>>>(xp_raw, pln_w, pln_b, xp);
  // 7. kvp_raw = xp @ kv_w^T + kv_b
  gemm_mfma<128, 1, bf16><<<dim3(4,98), 256, 0, stream>>>(xp, kv_wb, kv_b, nullptr, kvp_raw, ROWS_, 256);
  // 7.5 k_p rows + v_p planes  (kvp_raw dead after -> its slot becomes O partials)
  post_kvp_kernel<<<98, 256, 0, stream>>>(kvp_raw, k_p, v_p);
  // 8a. pool-attention partials, 2-way key split (784 blocks, ~12 waves/CU)
  attn_part_kernel<<<dim3(49,8,2), 256, 0, stream>>>(qs, k_p, v_p, Opart, Lpart);
  // 8b. combine + local 3x3 + tokens -> xo (bf16 rows in d_out)
  attn_combine_kernel<<<GQ_/256, 256, 0, stream>>>(Opart, Lpart, qs, kv_raw,
                                                   qe, temp, tokens, tbias, xo);
  // 9. x2 = x_in + (xo @ proj_w^T + proj_b)
  gemm_mfma<128, 4, float><<<dim3(2,98), 256, 0, stream>>>(xo, proj_wb, proj_b, x_in, x2, ROWS_, 128);
  // 10. y2 = LN2(x2)
  ln_kernel<float, bf16, true><<<ROWS_/4, 256, 0, stream>>>(x2, norm2_w, norm2_b, y2);
  // 11. MLP per batch
  for (int b = 0; b < B_; b++){
    gemm_mfma<128, 3, bf16><<<dim3(49,11), 256, 0, stream>>>(
        fc1_wb, y2 + (long)b*N_*C_, fc1_b, nullptr, f1b, 2*HF_, N_);
    dwconv_kernel<<<(N_*44+255)/256, 256, 0, stream>>>(f1b, dw_w, dw_b, g_rows);
    gemm_mfma<KF2, 5, float><<<dim3(49,2), 256, 0, stream>>>(
        fc2_wb, g_rows, fc2_b, x2 + (long)b*C_*N_,
        ((float*)d_out) + (long)b*C_*N_, C_, N_);
  }
}

// Round 11
// 335.680 us; speedup vs baseline: 3.6727x; 1.0231x over previous
//
#include <hip/hip_runtime.h>
#include <hip/hip_bf16.h>

typedef __hip_bfloat16 bf16;
typedef short s8v __attribute__((ext_vector_type(8)));   // 8 bf16 = 4 VGPR MFMA frag
typedef float f4v __attribute__((ext_vector_type(4)));   // 4 fp32 MFMA acc

#define DEVI __device__ __forceinline__

DEVI float cvt(float x){ return x; }
DEVI float cvt(bf16 x){ return __bfloat162float(x); }

DEVI void stg(float* p, float v){ *p = v; }
DEVI void stg(bf16* p, float v){ *p = __float2bfloat16(v); }

DEVI float gelu_exact(float x){
  return 0.5f*x*(1.0f + erff(x*0.70710678118654752440f));
}

// problem constants
constexpr int B_ = 2, C_ = 128, H_ = 56, W_ = 56, N_ = 3136, NH_ = 4, D_ = 32, HF_ = 341;
constexpr int ROWS_ = B_*N_;             // 6272
constexpr int KF2 = 352;                 // fc2 K padded 341 -> 352 (11*32)
constexpr int GQ_ = NH_*B_*N_;           // 25088 (bh*N + n)
constexpr int FW = 512;                  // fused qkv+sr output width (q 0..128 | kv 128..384 | sr 384..512)

// ---------------- LayerNorm (one wave per row of 128 channels) ----------------
// PLANES: x is (B,C,N) planes; else x rows with stride xstr. Output y rows stride 128.
template<typename TX, typename TY, bool PLANES>
__global__ __launch_bounds__(256)
void ln_kernel(const TX* __restrict__ x, long xstr, const float* __restrict__ w,
               const float* __restrict__ bia, TY* __restrict__ y)
{
  int gid = blockIdx.x*4 + (threadIdx.x>>6);      // row over B*N
  int lane = threadIdx.x & 63;
  int b = gid / N_, n = gid % N_;
  float v0, v1;
  if (PLANES){
    v0 = cvt(x[((long)b*C_ + lane     )*N_ + n]);
    v1 = cvt(x[((long)b*C_ + lane + 64)*N_ + n]);
  } else {
    v0 = cvt(x[(long)gid*xstr + lane     ]);
    v1 = cvt(x[(long)gid*xstr + lane + 64]);
  }
  float s = v0+v1, ss = v0*v0 + v1*v1;
  #pragma unroll
  for (int o=32;o>0;o>>=1){ s += __shfl_xor(s,o); ss += __shfl_xor(ss,o); }
  float mu  = s*(1.0f/128.0f);
  float var = fmaxf(ss*(1.0f/128.0f) - mu*mu, 0.f);
  float inv = rsqrtf(var + 1e-5f);
  stg(&y[(long)gid*C_ + lane     ], (v0-mu)*inv*w[lane     ] + bia[lane     ]);
  stg(&y[(long)gid*C_ + lane + 64], (v1-mu)*inv*w[lane + 64] + bia[lane + 64]);
}

// ---------------- weight fp32 -> bf16 conversion + combined qkvsr bias ----------------
__global__ __launch_bounds__(256)
void convw_kernel(const float* __restrict__ q_w, const float* __restrict__ kv_w,
                  const float* __restrict__ sr_w, const float* __restrict__ proj_w,
                  const float* __restrict__ fc1_w, const float* __restrict__ fc2_w,
                  const float* __restrict__ q_b, const float* __restrict__ kv_b,
                  const float* __restrict__ sr_b,
                  bf16* __restrict__ out, float* __restrict__ bias_out)
{
  int t = blockIdx.x*256 + threadIdx.x;
  if (t >= 214272){
    int i = t - 214272;
    if (i < 512){
      float bv = (i < 128) ? q_b[i] : (i < 384) ? kv_b[i-128] : sr_b[i-384];
      bias_out[i] = bv;
    }
    return;
  }
  float v;
  if      (t <  16384) v = q_w[t];
  else if (t <  49152) v = kv_w[t-16384];
  else if (t <  65536) v = sr_w[t-49152];
  else if (t <  81920) v = proj_w[t-65536];
  else if (t < 169216) v = fc1_w[t-81920];
  else {
    int i = t - 169216; int m = i / KF2, kp = i % KF2;
    v = (kp < HF_) ? fc2_w[m*HF_ + kp] : 0.f;
  }
  out[t] = __float2bfloat16(v);
}

// ---------------- LDS-free MFMA GEMM ----------------
// MODE: 1=+bias[n]; 2=+bias[n]+gelu; 3=+bias[m]; 4=+bias[n]+res fp32; 5=+bias[m]+res fp32;
//       6=+bias[n], gelu iff n>=384 (fused qkv|sr epilogue)
template<int KT, int MODE, typename TC>
__global__ __launch_bounds__(256)
void gemm_mfma(const bf16* __restrict__ A, const bf16* __restrict__ B,
               const float* __restrict__ bias, const float* __restrict__ res,
               TC* __restrict__ Cm, int M, int Nn)
{
  int lane = threadIdx.x & 63, w = threadIdx.x >> 6;
  int m = lane & 15, quad = lane >> 4;
  int n0 = blockIdx.x*64, m0 = blockIdx.y*64;
  int arow = m0 + w*16 + m;
  if (arow >= M) arow = M-1;                    // clamp loads; stores guarded
  const bf16* ap = A + (long)arow*KT + quad*8;
  const bf16* bp = B + (long)(n0 + m)*KT + quad*8;
  f4v acc[4];
  #pragma unroll
  for (int s=0;s<4;s++) acc[s] = (f4v){0.f,0.f,0.f,0.f};
  #pragma unroll
  for (int k0 = 0; k0 < KT; k0 += 32){
    s8v af = *(const s8v*)(ap + k0);
    #pragma unroll
    for (int s=0;s<4;s++){
      s8v bf = *(const s8v*)(bp + (long)s*16*KT + k0);
      acc[s] = __builtin_amdgcn_mfma_f32_16x16x32_bf16(af, bf, acc[s], 0, 0, 0);
    }
  }
  #pragma unroll
  for (int s=0;s<4;s++){
    int gn = n0 + s*16 + m;
    #pragma unroll
    for (int r=0;r<4;r++){
      int gm = m0 + w*16 + quad*4 + r;
      if (gm >= M) continue;
      float v = acc[s][r];
      if (MODE==1 || MODE==2 || MODE==4 || MODE==6) v += bias[gn];
      else                                          v += bias[gm];
      if (MODE==2) v = gelu_exact(v);
      if (MODE==6 && gn >= 384) v = gelu_exact(v);
      if (MODE==4 || MODE==5) v += res[(long)gm*Nn + gn];
      stg(&Cm[(long)gm*Nn + gn], v);
    }
  }
}

// ---------------- q post-process: l2n + embed + temperature -> qs ROWS ----------------
// q_raw = fused rows (stride FW, cols 0..128)
__global__ __launch_bounds__(256)
void post_q_kernel(const bf16* __restrict__ fused, const float* __restrict__ qe,
                   const float* __restrict__ temp, bf16* __restrict__ qs)
{
  int t = blockIdx.x*256 + threadIdx.x;        // (b*4+h)*N + n
  int n = t % N_; int bh = t / N_; int h = bh & 3; int b = bh >> 2;
  float sp = log1pf(expf(temp[h]));
  const bf16* qr = fused + ((long)(b*N_ + n))*FW + h*D_;
  float v[32]; float ss = 0.f;
  #pragma unroll
  for (int d=0;d<32;d++){ v[d] = cvt(qr[d]); ss = fmaf(v[d], v[d], ss); }
  float inv = 1.f/fmaxf(sqrtf(ss), 1e-12f);
  bf16* qo = qs + ((long)bh*N_ + n)*D_;
  #pragma unroll
  for (int d=0;d<32;d++)
    stg(&qo[d], (v[d]*inv + qe[h*D_+d])*sp);
}

// ---------------- pooled kv post-process ----------------
__global__ __launch_bounds__(256)
void post_kvp_kernel(const bf16* __restrict__ kvp_raw,
                     bf16* __restrict__ kp, bf16* __restrict__ vp)
{
  int t = blockIdx.x*256 + threadIdx.x;        // bh*N + n
  int n = t % N_; int bh = t / N_; int h = bh & 3; int b = bh >> 2;
  const bf16* kr = kvp_raw + ((long)(b*N_ + n))*(2*C_) + h*D_;
  float v[32]; float ss = 0.f;
  #pragma unroll
  for (int d=0;d<32;d++){ v[d] = cvt(kr[d]); ss = fmaf(v[d], v[d], ss); }
  float inv = 1.f/fmaxf(sqrtf(ss), 1e-12f);
  bf16* ko = kp + ((long)bh*N_ + n)*D_;
  #pragma unroll
  for (int d=0;d<32;d++) stg(&ko[d], v[d]*inv);
  #pragma unroll
  for (int d=0;d<32;d++) vp[((long)bh*D_ + d)*N_ + n] = kr[C_ + d];
}

// ---------------- MFMA pool-attention PARTIAL (2-way key split, reg prefetch) -------
// grid (49, 8, 2); block 256 = 4 waves; wave owns 16 queries.
// Tile t+1's 8 K/V fragments are loaded into registers BEFORE computing tile t,
// so the global-load latency overlaps the MFMA/exp/LDS work of the current tile.
__global__ __launch_bounds__(256)
void attn_part_kernel(const bf16* __restrict__ qs_, const bf16* __restrict__ kp_,
                      const bf16* __restrict__ vp_,
                      bf16* __restrict__ Op, float* __restrict__ Lp)
{
  int bh = blockIdx.y;
  int z  = blockIdx.z;
  int lane = threadIdx.x & 63;
  int w    = threadIdx.x >> 6;
  int m    = lane & 15, quad = lane >> 4;
  int q0   = blockIdx.x*64 + w*16;
  __shared__ float sm[4][608];                 // per-wave: P 16x72 bf16 | O 16x36 f32 + L 16
  bf16*  Plds = (bf16*)sm[w];
  float* Olds = sm[w];

  s8v afrag = *(const s8v*)(qs_ + ((long)bh*N_ + q0 + m)*D_ + quad*8);
  const bf16* kpb = kp_ + (long)bh*N_*D_;
  const bf16* vpb = vp_ + (long)bh*D_*N_;
  f4v oacc0 = {0.f,0.f,0.f,0.f}, oacc1 = {0.f,0.f,0.f,0.f};
  float lacc[4] = {0.f,0.f,0.f,0.f};

  int tlo = z*1600, thi = min(tlo + 1600, N_);
  s8v kf[4], vf[4], kn[4], vn[4];
  #pragma unroll
  for (int s=0;s<4;s++)
    kf[s] = *(const s8v*)(kpb + (long)(tlo + s*16 + m)*D_ + quad*8);
  vf[0] = *(const s8v*)(vpb + (long)(m     )*N_ + tlo      + quad*8);
  vf[1] = *(const s8v*)(vpb + (long)(16 + m)*N_ + tlo      + quad*8);
  vf[2] = *(const s8v*)(vpb + (long)(m     )*N_ + tlo + 32 + quad*8);
  vf[3] = *(const s8v*)(vpb + (long)(16 + m)*N_ + tlo + 32 + quad*8);

  for (int t0 = tlo; t0 < thi; t0 += 64){
    int t1 = t0 + 64; if (t1 >= thi) t1 = t0;
    // prefetch next tile (stays in flight during this tile's compute)
    #pragma unroll
    for (int s=0;s<4;s++)
      kn[s] = *(const s8v*)(kpb + (long)(t1 + s*16 + m)*D_ + quad*8);
    vn[0] = *(const s8v*)(vpb + (long)(m     )*N_ + t1      + quad*8);
    vn[1] = *(const s8v*)(vpb + (long)(16 + m)*N_ + t1      + quad*8);
    vn[2] = *(const s8v*)(vpb + (long)(m     )*N_ + t1 + 32 + quad*8);
    vn[3] = *(const s8v*)(vpb + (long)(16 + m)*N_ + t1 + 32 + quad*8);
    // compute current tile
    float p[4][4];
    #pragma unroll
    for (int s = 0; s < 4; s++){
      f4v c = {0.f,0.f,0.f,0.f};
      c = __builtin_amdgcn_mfma_f32_16x16x32_bf16(afrag, kf[s], c, 0, 0, 0);
      #pragma unroll
      for (int r=0;r<4;r++){
        float e = __expf(c[r] - 8.f);          // D: row=quad*4+r (query), col=m (key)
        lacc[r] += e;
        p[s][r] = e;
      }
    }
    #pragma unroll
    for (int s=0;s<4;s++)
      #pragma unroll
      for (int r=0;r<4;r++)
        Plds[(quad*4+r)*72 + s*16 + m] = __float2bfloat16(p[s][r]);
    #pragma unroll
    for (int c2=0;c2<2;c2++){
      s8v pa = *(const s8v*)(Plds + m*72 + c2*32 + quad*8);
      oacc0 = __builtin_amdgcn_mfma_f32_16x16x32_bf16(pa, vf[c2*2  ], oacc0, 0, 0, 0);
      oacc1 = __builtin_amdgcn_mfma_f32_16x16x32_bf16(pa, vf[c2*2+1], oacc1, 0, 0, 0);
    }
    #pragma unroll
    for (int s=0;s<4;s++){ kf[s] = kn[s]; vf[s] = vn[s]; }
  }
  #pragma unroll
  for (int off=1; off<16; off<<=1)
    #pragma unroll
    for (int r=0;r<4;r++) lacc[r] += __shfl_xor(lacc[r], off);
  #pragma unroll
  for (int r=0;r<4;r++){
    Olds[(quad*4+r)*36 + m     ] = oacc0[r];
    Olds[(quad*4+r)*36 + 16 + m] = oacc1[r];
  }
  if (m == 0){
    #pragma unroll
    for (int r=0;r<4;r++) Olds[576 + quad*4 + r] = lacc[r];
  }
  // lane remap: query = m, dim-group = quad; coalesced 16B partial store
  long gq = (long)bh*N_ + q0 + m;
  f4v ov0 = *(const f4v*)(Olds + m*36 + quad*8);
  f4v ov1 = *(const f4v*)(Olds + m*36 + quad*8 + 4);
  bf16 o8[8];
  #pragma unroll
  for (int j=0;j<4;j++){ o8[j] = __float2bfloat16(ov0[j]); o8[4+j] = __float2bfloat16(ov1[j]); }
  *(s8v*)(Op + ((long)z*GQ_ + gq)*32 + quad*8) = *(const s8v*)o8;
  if (quad == 0) Lp[(long)z*GQ_ + gq] = Olds[576 + m];
}

// ---------------- combine partials + local 3x3 + learnable tokens -> xo rows --------
// kv rows now live inside the fused buffer: row stride FW, key cols 128.., value cols 256..
__global__ __launch_bounds__(256)
void attn_combine_kernel(const bf16* __restrict__ Op, const float* __restrict__ Lp,
                         const bf16* __restrict__ qs_, const bf16* __restrict__ fused,
                         const float* __restrict__ qe, const float* __restrict__ temp,
                         const float* __restrict__ tokens, const float* __restrict__ tbias,
                         bf16* __restrict__ xo)
{
  int gq = blockIdx.x*256 + threadIdx.x;       // bh*N + n, 25088 total
  int n = gq % N_; int bh = gq / N_; int h = bh & 3; int b = bh >> 2;
  float L = Lp[gq] + Lp[GQ_ + gq];
  const bf16* o0 = Op + (long)gq*32;
  const bf16* o1 = Op + ((long)GQ_ + gq)*32;
  float out[32];
  #pragma unroll
  for (int d=0;d<32;d++) out[d] = cvt(o0[d]) + cvt(o1[d]);
  const bf16* qrow = qs_ + (long)gq*D_;
  float q[32];
  #pragma unroll
  for (int d=0;d<32;d++) q[d] = cvt(qrow[d]);
  int hy = n / W_, wx = n % W_;
  const bf16* kvb = fused + (long)b*N_*FW + 128 + h*D_;   // key cols
  float sl[9];
  #pragma unroll
  for (int k=0;k<9;k++){
    int di = k/3-1, dj = k%3-1;
    int yy = hy+di, xx = wx+dj;
    float s = 0.f;
    if (yy>=0 && yy<H_ && xx>=0 && xx<W_){
      long nn2 = (long)(yy*W_+xx)*FW;
      float dot = 0.f, ss = 0.f;
      #pragma unroll
      for (int d=0;d<32;d++){
        float kk = cvt(kvb[nn2 + d]);
        dot = fmaf(q[d], kk, dot);
        ss  = fmaf(kk, kk, ss);
      }
      s = dot / fmaxf(sqrtf(ss), 1e-12f);
    }
    sl[k] = s;                                  // OOB: exactly 0 (zero-padded key)
  }
  #pragma unroll
  for (int k=0;k<9;k++) L += __expf(sl[k] - 8.f);
  float invL = 1.f/L;
  #pragma unroll
  for (int d=0;d<32;d++) out[d] *= invL;
  float sp = log1pf(expf(temp[h]));
  float invsp = 1.f/sp;
  float qn[32];
  #pragma unroll
  for (int d=0;d<32;d++) qn[d] = q[d]*invsp - qe[h*D_+d];
  #pragma unroll
  for (int k=0;k<9;k++){
    float tok = 0.f;
    #pragma unroll
    for (int d=0;d<32;d++) tok = fmaf(qn[d], tokens[(h*D_+d)*9+k], tok);
    float wl = tok + tbias[h*9+k] + __expf(sl[k] - 8.f)*invL;
    int di = k/3-1, dj = k%3-1;
    int yy = hy+di, xx = wx+dj;
    if (yy>=0 && yy<H_ && xx>=0 && xx<W_){      // OOB v_l zero-padded -> contributes 0
      long nn2 = (long)(yy*W_+xx)*FW;
      #pragma unroll
      for (int d=0;d<32;d++) out[d] = fmaf(wl, cvt(kvb[nn2 + 128 + d]), out[d]);
    }
  }
  bf16* op = xo + ((long)(b*N_ + n))*C_ + h*D_;
  #pragma unroll
  for (int d=0;d<32;d++) stg(&op[d], out[d]);
}

// ---------------- depthwise 3x3 + bias + gelu, gated -> g ROWS (n, 352) ----------------
// COALESCED mapping: n fastest (consecutive lanes -> consecutive n); cg wave-uniform.
__global__ __launch_bounds__(256)
void dwconv_kernel(const bf16* __restrict__ f1, const float* __restrict__ dww,
                   const float* __restrict__ dwb, bf16* __restrict__ g)
{
  int t = blockIdx.x*256 + threadIdx.x;
  if (t >= N_*44) return;
  int n = t % N_, cg = t / N_;
  int c0 = cg*8;
  int hy = n / W_, wx = n % W_;
  bf16 o8[8];
  #pragma unroll
  for (int j=0;j<8;j++){
    int c = c0 + j;
    float val = 0.f;
    if (c < HF_){
      const bf16* ap = f1 + (long)c*N_;
      float s = dwb[c];
      #pragma unroll
      for (int di=-1; di<=1; di++)
        #pragma unroll
        for (int dj=-1; dj<=1; dj++){
          int yy = hy+di, xx = wx+dj;
          if (yy>=0 && yy<H_ && xx>=0 && xx<W_)
            s = fmaf(dww[c*9 + (di+1)*3 + (dj+1)], cvt(ap[yy*W_+xx]), s);
        }
      val = gelu_exact(s) * cvt(f1[(long)(HF_+c)*N_ + n]);
    }
    o8[j] = __float2bfloat16(val);
  }
  *(s8v*)(g + (long)n*KF2 + c0) = *(const s8v*)o8;
}

// ---------------- launcher ----------------
extern "C" void kernel_launch(void* const* d_in, const int* in_sizes, int n_in,
                              void* d_out, int out_size, void* d_ws, size_t ws_size,
                              hipStream_t stream)
{
  (void)in_sizes; (void)n_in; (void)out_size; (void)ws_size;
  const float* x_in      = (const float*)d_in[0];
  const float* norm1_w   = (const float*)d_in[1];
  const float* norm1_b   = (const float*)d_in[2];
  const float* q_w       = (const float*)d_in[3];
  const float* q_b       = (const float*)d_in[4];
  const float* kv_w      = (const float*)d_in[5];
  const float* kv_b      = (const float*)d_in[6];
  const float* temp      = (const float*)d_in[7];
  const float* qe        = (const float*)d_in[8];
  const float* tokens    = (const float*)d_in[9];
  const float* tbias     = (const float*)d_in[10];
  const float* sr_w      = (const float*)d_in[11];
  const float* sr_b      = (const float*)d_in[12];
  const float* pln_w     = (const float*)d_in[13];
  const float* pln_b     = (const float*)d_in[14];
  const float* proj_w    = (const float*)d_in[15];
  const float* proj_b    = (const float*)d_in[16];
  const float* norm2_w   = (const float*)d_in[17];
  const float* norm2_b   = (const float*)d_in[18];
  const float* fc1_w     = (const float*)d_in[19];
  const float* fc1_b     = (const float*)d_in[20];
  const float* dw_w      = (const float*)d_in[21];
  const float* dw_b      = (const float*)d_in[22];
  const float* fc2_w     = (const float*)d_in[23];
  const float* fc2_b     = (const float*)d_in[24];

  // ---- workspace plan (bytes), peak 14,881,280 (14.2 MiB) ----
  // F [0, 6422528):         fused qkv|sr bf16 rows (6272 x 512)
  //                         -> after combine: x2 fp32 [0,3211264) + y2 bf16 [3211264,4816896)
  //                         -> f1b bf16 planes (682,N) per batch [4816896,9094400)
  // C [6422528, 8028160):   qs bf16 rows (alive through combine)
  // D [8028160, 9633792):   xp rows -> k_p rows
  // E [9633792, 11239424):  v_p planes; later g rows (N,352) per batch [9633792,11841536)
  // B [11239424, 14450688): kvp_raw rows -> Opart (2 x 25088 x 32 bf16, exact fit)
  // W [14450688, 14879232): bf16 weights; [14879232,14881280): combined qkvsr bias f32
  // d_out: xo bf16 rows [0,1605632) + Lpart f32 [1605632,1806336); overwritten by fc2.
  char* w8 = (char*)d_ws;
  bf16*  fused   = (bf16*)(w8 + 0);
  float* x2      = (float*)(w8 + 0);
  bf16*  y2      = (bf16*)(w8 + 3211264);
  bf16*  f1b     = (bf16*)(w8 + 4816896);
  bf16*  qs      = (bf16*)(w8 + 6422528);
  bf16*  xp      = (bf16*)(w8 + 8028160);
  bf16*  k_p     = (bf16*)(w8 + 8028160);
  bf16*  v_p     = (bf16*)(w8 + 9633792);
  bf16*  g_rows  = (bf16*)(w8 + 9633792);
  bf16*  kvp_raw = (bf16*)(w8 + 11239424);
  bf16*  Opart   = (bf16*)(w8 + 11239424);
  bf16*  wbase   = (bf16*)(w8 + 14450688);
  float* fbias   = (float*)(w8 + 14879232);
  bf16*  y       = f1b;                         // LN1 output rows (dead before f1b use)
  bf16*  xo      = (bf16*)d_out;
  float* Lpart   = (float*)((char*)d_out + 1605632);
  bf16*  proj_wb = wbase + 65536;
  bf16*  fc1_wb  = wbase + 81920;
  bf16*  fc2_wb  = wbase + 169216;

  // 0. weights -> bf16 (fc2 K-padded) + combined qkvsr bias
  convw_kernel<<<(214784+255)/256, 256, 0, stream>>>(
      q_w, kv_w, sr_w, proj_w, fc1_w, fc2_w, q_b, kv_b, sr_b, wbase, fbias);
  // 1. y = LN1(x)   (fp32 planes -> bf16 rows at slot f1b, dead before MLP)
  ln_kernel<float, bf16, true><<<ROWS_/4, 256, 0, stream>>>(x_in, 0, norm1_w, norm1_b, y);
  // 2. fused = y @ [q_w; kv_w; sr_w]^T + [q_b;kv_b;sr_b], gelu on sr cols (384..512)
  gemm_mfma<128, 6, bf16><<<dim3(8,98), 256, 0, stream>>>(y, wbase, fbias, nullptr, fused, ROWS_, FW);
  // 3. qs rows (reads fused q cols)
  post_q_kernel<<<98, 256, 0, stream>>>(fused, qe, temp, qs);
  // 4. xp = LN_pln(fused sr cols)  (rows stride 512 -> rows stride 128)
  ln_kernel<bf16, bf16, false><<<ROWS_/4, 256, 0, stream>>>(fused + 384, FW, pln_w, pln_b, xp);
  // 5. kvp_raw = xp @ kv_w^T + kv_b
  gemm_mfma<128, 1, bf16><<<dim3(4,98), 256, 0, stream>>>(xp, wbase + 16384, kv_b, nullptr, kvp_raw, ROWS_, 256);
  // 6. k_p rows (overwrites xp) + v_p planes
  post_kvp_kernel<<<98, 256, 0, stream>>>(kvp_raw, k_p, v_p);
  // 7. pool-attention partials (2-way key split, register-prefetch pipeline)
  attn_part_kernel<<<dim3(49,8,2), 256, 0, stream>>>(qs, k_p, v_p, Opart, Lpart);
  // 8. combine + local 3x3 + tokens -> xo (bf16 rows in d_out)
  attn_combine_kernel<<<GQ_/256, 256, 0, stream>>>(Opart, Lpart, qs, fused,
                                                   qe, temp, tokens, tbias, xo);
  // 9. x2 = x_in + (xo @ proj_w^T + proj_b)   (flat-reinterpret residual)
  gemm_mfma<128, 4, float><<<dim3(2,98), 256, 0, stream>>>(xo, proj_wb, proj_b, x_in, x2, ROWS_, 128);
  // 10. y2 = LN2(x2)
  ln_kernel<float, bf16, true><<<ROWS_/4, 256, 0, stream>>>(x2, 0, norm2_w, norm2_b, y2);
  // 11. MLP per batch
  for (int b = 0; b < B_; b++){
    gemm_mfma<128, 3, bf16><<<dim3(49,11), 256, 0, stream>>>(
        fc1_wb, y2 + (long)b*N_*C_, fc1_b, nullptr, f1b, 2*HF_, N_);
    dwconv_kernel<<<(N_*44+255)/256, 256, 0, stream>>>(f1b, dw_w, dw_b, g_rows);
    gemm_mfma<KF2, 5, float><<<dim3(49,2), 256, 0, stream>>>(
        fc2_wb, g_rows, fc2_b, x2 + (long)b*C_*N_,
        ((float*)d_out) + (long)b*C_*N_, C_, N_);
  }
}

// Round 13
// 302.321 us; speedup vs baseline: 4.0779x; 1.1103x over previous
//
#include <hip/hip_runtime.h>
#include <hip/hip_bf16.h>

typedef __hip_bfloat16 bf16;
typedef short s8v __attribute__((ext_vector_type(8)));   // 8 bf16 = 4 VGPR MFMA frag
typedef float f4v __attribute__((ext_vector_type(4)));   // 4 fp32 MFMA acc

#define DEVI __device__ __forceinline__

DEVI float cvt(float x){ return x; }
DEVI float cvt(bf16 x){ return __bfloat162float(x); }

DEVI void stg(float* p, float v){ *p = v; }
DEVI void stg(bf16* p, float v){ *p = __float2bfloat16(v); }

DEVI float gelu_exact(float x){
  return 0.5f*x*(1.0f + erff(x*0.70710678118654752440f));
}

// problem constants
constexpr int B_ = 2, C_ = 128, H_ = 56, W_ = 56, N_ = 3136, NH_ = 4, D_ = 32, HF_ = 341;
constexpr int ROWS_ = B_*N_;             // 6272
constexpr int KF2 = 352;                 // fc2 K padded 341 -> 352 (11*32)
constexpr int GQ_ = NH_*B_*N_;           // 25088 (bh*N + n)
constexpr int FW = 512;                  // fused qkv+sr output width (q 0..128 | kv 128..384 | sr 384..512)

// ---------------- LayerNorm (one wave per row of 128 channels) ----------------
template<typename TX, typename TY, bool PLANES>
__global__ __launch_bounds__(256)
void ln_kernel(const TX* __restrict__ x, long xstr, const float* __restrict__ w,
               const float* __restrict__ bia, TY* __restrict__ y)
{
  int gid = blockIdx.x*4 + (threadIdx.x>>6);      // row over B*N
  int lane = threadIdx.x & 63;
  int b = gid / N_, n = gid % N_;
  float v0, v1;
  if (PLANES){
    v0 = cvt(x[((long)b*C_ + lane     )*N_ + n]);
    v1 = cvt(x[((long)b*C_ + lane + 64)*N_ + n]);
  } else {
    v0 = cvt(x[(long)gid*xstr + lane     ]);
    v1 = cvt(x[(long)gid*xstr + lane + 64]);
  }
  float s = v0+v1, ss = v0*v0 + v1*v1;
  #pragma unroll
  for (int o=32;o>0;o>>=1){ s += __shfl_xor(s,o); ss += __shfl_xor(ss,o); }
  float mu  = s*(1.0f/128.0f);
  float var = fmaxf(ss*(1.0f/128.0f) - mu*mu, 0.f);
  float inv = rsqrtf(var + 1e-5f);
  stg(&y[(long)gid*C_ + lane     ], (v0-mu)*inv*w[lane     ] + bia[lane     ]);
  stg(&y[(long)gid*C_ + lane + 64], (v1-mu)*inv*w[lane + 64] + bia[lane + 64]);
}

// ---------------- weight fp32 -> bf16 conversion + combined qkvsr bias ----------------
__global__ __launch_bounds__(256)
void convw_kernel(const float* __restrict__ q_w, const float* __restrict__ kv_w,
                  const float* __restrict__ sr_w, const float* __restrict__ proj_w,
                  const float* __restrict__ fc1_w, const float* __restrict__ fc2_w,
                  const float* __restrict__ q_b, const float* __restrict__ kv_b,
                  const float* __restrict__ sr_b,
                  bf16* __restrict__ out, float* __restrict__ bias_out)
{
  int t = blockIdx.x*256 + threadIdx.x;
  if (t >= 214272){
    int i = t - 214272;
    if (i < 512){
      float bv = (i < 128) ? q_b[i] : (i < 384) ? kv_b[i-128] : sr_b[i-384];
      bias_out[i] = bv;
    }
    return;
  }
  float v;
  if      (t <  16384) v = q_w[t];
  else if (t <  49152) v = kv_w[t-16384];
  else if (t <  65536) v = sr_w[t-49152];
  else if (t <  81920) v = proj_w[t-65536];
  else if (t < 169216) v = fc1_w[t-81920];
  else {
    int i = t - 169216; int m = i / KF2, kp = i % KF2;
    v = (kp < HF_) ? fc2_w[m*HF_ + kp] : 0.f;
  }
  out[t] = __float2bfloat16(v);
}

// ---------------- LDS-free MFMA GEMM ----------------
// MODE: 1=+bias[n]; 2=+bias[n]+gelu; 3=+bias[m]; 4=+bias[n]+res fp32; 5=+bias[m]+res fp32;
//       6=+bias[n], gelu iff n>=384 (fused qkv|sr epilogue)
template<int KT, int MODE, typename TC>
__global__ __launch_bounds__(256)
void gemm_mfma(const bf16* __restrict__ A, const bf16* __restrict__ B,
               const float* __restrict__ bias, const float* __restrict__ res,
               TC* __restrict__ Cm, int M, int Nn)
{
  int lane = threadIdx.x & 63, w = threadIdx.x >> 6;
  int m = lane & 15, quad = lane >> 4;
  int n0 = blockIdx.x*64, m0 = blockIdx.y*64;
  int arow = m0 + w*16 + m;
  if (arow >= M) arow = M-1;                    // clamp loads; stores guarded
  const bf16* ap = A + (long)arow*KT + quad*8;
  const bf16* bp = B + (long)(n0 + m)*KT + quad*8;
  f4v acc[4];
  #pragma unroll
  for (int s=0;s<4;s++) acc[s] = (f4v){0.f,0.f,0.f,0.f};
  #pragma unroll
  for (int k0 = 0; k0 < KT; k0 += 32){
    s8v af = *(const s8v*)(ap + k0);
    #pragma unroll
    for (int s=0;s<4;s++){
      s8v bf = *(const s8v*)(bp + (long)s*16*KT + k0);
      acc[s] = __builtin_amdgcn_mfma_f32_16x16x32_bf16(af, bf, acc[s], 0, 0, 0);
    }
  }
  #pragma unroll
  for (int s=0;s<4;s++){
    int gn = n0 + s*16 + m;
    #pragma unroll
    for (int r=0;r<4;r++){
      int gm = m0 + w*16 + quad*4 + r;
      if (gm >= M) continue;
      float v = acc[s][r];
      if (MODE==1 || MODE==2 || MODE==4 || MODE==6) v += bias[gn];
      else                                          v += bias[gm];
      if (MODE==2) v = gelu_exact(v);
      if (MODE==6 && gn >= 384) v = gelu_exact(v);
      if (MODE==4 || MODE==5) v += res[(long)gm*Nn + gn];
      stg(&Cm[(long)gm*Nn + gn], v);
    }
  }
}

// ---------------- q post-process: l2n + embed + temperature -> qs ROWS ----------------
__global__ __launch_bounds__(256)
void post_q_kernel(const bf16* __restrict__ fused, const float* __restrict__ qe,
                   const float* __restrict__ temp, bf16* __restrict__ qs)
{
  int t = blockIdx.x*256 + threadIdx.x;        // (b*4+h)*N + n
  int n = t % N_; int bh = t / N_; int h = bh & 3; int b = bh >> 2;
  float sp = log1pf(expf(temp[h]));
  const bf16* qr = fused + ((long)(b*N_ + n))*FW + h*D_;
  float v[32]; float ss = 0.f;
  #pragma unroll
  for (int d=0;d<32;d++){ v[d] = cvt(qr[d]); ss = fmaf(v[d], v[d], ss); }
  float inv = 1.f/fmaxf(sqrtf(ss), 1e-12f);
  bf16* qo = qs + ((long)bh*N_ + n)*D_;
  #pragma unroll
  for (int d=0;d<32;d++)
    stg(&qo[d], (v[d]*inv + qe[h*D_+d])*sp);
}

// ---------------- pooled kv post-process ----------------
__global__ __launch_bounds__(256)
void post_kvp_kernel(const bf16* __restrict__ kvp_raw,
                     bf16* __restrict__ kp, bf16* __restrict__ vp)
{
  int t = blockIdx.x*256 + threadIdx.x;        // bh*N + n
  int n = t % N_; int bh = t / N_; int h = bh & 3; int b = bh >> 2;
  const bf16* kr = kvp_raw + ((long)(b*N_ + n))*(2*C_) + h*D_;
  float v[32]; float ss = 0.f;
  #pragma unroll
  for (int d=0;d<32;d++){ v[d] = cvt(kr[d]); ss = fmaf(v[d], v[d], ss); }
  float inv = 1.f/fmaxf(sqrtf(ss), 1e-12f);
  bf16* ko = kp + ((long)bh*N_ + n)*D_;
  #pragma unroll
  for (int d=0;d<32;d++) stg(&ko[d], v[d]*inv);
  #pragma unroll
  for (int d=0;d<32;d++) vp[((long)bh*D_ + d)*N_ + n] = kr[C_ + d];
}

// ---------------- MFMA pool-attention PARTIAL (2 q-tiles/wave, shared K/V frags) ----
// grid (25, 8, 2); block 256 = 4 waves. Wave w owns q-tiles qA = bx*128 + w*16 and
// qB = qA+64 (B guarded at the 3136 tail). Per 64-key tile, the 8 K/V fragment loads
// feed 16 MFMAs (2 independent QK->exp->LDS->PV chains share them) -> 2x arithmetic
// intensity + intra-wave ILP to hide the chain latency. No explicit prefetch (proven
// neutral in round 11). No __syncthreads anywhere (wave-private LDS regions).
__global__ __launch_bounds__(256)
void attn_part_kernel(const bf16* __restrict__ qs_, const bf16* __restrict__ kp_,
                      const bf16* __restrict__ vp_,
                      bf16* __restrict__ Op, float* __restrict__ Lp)
{
  int bh = blockIdx.y;
  int z  = blockIdx.z;
  int lane = threadIdx.x & 63;
  int w    = threadIdx.x >> 6;
  int m    = lane & 15, quad = lane >> 4;
  int qA   = blockIdx.x*128 + w*16;
  int qB   = qA + 64;
  bool hasB = (qB < N_);
  __shared__ float sm[4][1184];                // per wave: PA 16x72 bf16 | PB 16x72 bf16 ; Olds reuses
  bf16*  PA   = (bf16*)sm[w];
  bf16*  PB   = PA + 1152;
  float* Olds = sm[w];

  s8v afA = *(const s8v*)(qs_ + ((long)bh*N_ + qA + m)*D_ + quad*8);
  s8v afB = hasB ? *(const s8v*)(qs_ + ((long)bh*N_ + qB + m)*D_ + quad*8) : afA;
  const bf16* kpb = kp_ + (long)bh*N_*D_;
  const bf16* vpb = vp_ + (long)bh*D_*N_;
  f4v oA0={0.f,0.f,0.f,0.f}, oA1={0.f,0.f,0.f,0.f};
  f4v oB0={0.f,0.f,0.f,0.f}, oB1={0.f,0.f,0.f,0.f};
  float lA[4]={0.f,0.f,0.f,0.f}, lB[4]={0.f,0.f,0.f,0.f};

  int tlo = z*1600, thi = min(tlo + 1600, N_);
  for (int t0 = tlo; t0 < thi; t0 += 64){
    s8v kf[4], vf[4];
    #pragma unroll
    for (int s=0;s<4;s++)
      kf[s] = *(const s8v*)(kpb + (long)(t0 + s*16 + m)*D_ + quad*8);
    vf[0] = *(const s8v*)(vpb + (long)(m     )*N_ + t0      + quad*8);
    vf[1] = *(const s8v*)(vpb + (long)(16 + m)*N_ + t0      + quad*8);
    vf[2] = *(const s8v*)(vpb + (long)(m     )*N_ + t0 + 32 + quad*8);
    vf[3] = *(const s8v*)(vpb + (long)(16 + m)*N_ + t0 + 32 + quad*8);
    // two independent QK chains sharing kf
    #pragma unroll
    for (int s = 0; s < 4; s++){
      f4v cA = {0.f,0.f,0.f,0.f}, cB = {0.f,0.f,0.f,0.f};
      cA = __builtin_amdgcn_mfma_f32_16x16x32_bf16(afA, kf[s], cA, 0, 0, 0);
      cB = __builtin_amdgcn_mfma_f32_16x16x32_bf16(afB, kf[s], cB, 0, 0, 0);
      #pragma unroll
      for (int r=0;r<4;r++){
        float eA = __expf(cA[r] - 8.f);        // D: row=quad*4+r (query), col=m (key)
        float eB = __expf(cB[r] - 8.f);
        lA[r] += eA; lB[r] += eB;
        PA[(quad*4+r)*72 + s*16 + m] = __float2bfloat16(eA);
        PB[(quad*4+r)*72 + s*16 + m] = __float2bfloat16(eB);
      }
    }
    // PV for both chains sharing vf
    #pragma unroll
    for (int c2=0;c2<2;c2++){
      s8v paA = *(const s8v*)(PA + m*72 + c2*32 + quad*8);
      s8v paB = *(const s8v*)(PB + m*72 + c2*32 + quad*8);
      oA0 = __builtin_amdgcn_mfma_f32_16x16x32_bf16(paA, vf[c2*2  ], oA0, 0, 0, 0);
      oA1 = __builtin_amdgcn_mfma_f32_16x16x32_bf16(paA, vf[c2*2+1], oA1, 0, 0, 0);
      oB0 = __builtin_amdgcn_mfma_f32_16x16x32_bf16(paB, vf[c2*2  ], oB0, 0, 0, 0);
      oB1 = __builtin_amdgcn_mfma_f32_16x16x32_bf16(paB, vf[c2*2+1], oB1, 0, 0, 0);
    }
  }
  // merge + store, phase 0 = A, phase 1 = B (wave-private, sequential reuse of Olds)
  #pragma unroll
  for (int ph=0; ph<2; ph++){
    if (ph == 1 && !hasB) break;
    float* lacc = ph ? lB : lA;
    f4v    o0   = ph ? oB0 : oA0;
    f4v    o1   = ph ? oB1 : oA1;
    int    qq   = ph ? qB  : qA;
    float lr[4] = {lacc[0], lacc[1], lacc[2], lacc[3]};
    #pragma unroll
    for (int off=1; off<16; off<<=1)
      #pragma unroll
      for (int r=0;r<4;r++) lr[r] += __shfl_xor(lr[r], off);
    #pragma unroll
    for (int r=0;r<4;r++){
      Olds[(quad*4+r)*36 + m     ] = o0[r];
      Olds[(quad*4+r)*36 + 16 + m] = o1[r];
    }
    if (m == 0){
      #pragma unroll
      for (int r=0;r<4;r++) Olds[576 + quad*4 + r] = lr[r];
    }
    long gq = (long)bh*N_ + qq + m;
    f4v ov0 = *(const f4v*)(Olds + m*36 + quad*8);
    f4v ov1 = *(const f4v*)(Olds + m*36 + quad*8 + 4);
    bf16 o8[8];
    #pragma unroll
    for (int j=0;j<4;j++){ o8[j] = __float2bfloat16(ov0[j]); o8[4+j] = __float2bfloat16(ov1[j]); }
    *(s8v*)(Op + ((long)z*GQ_ + gq)*32 + quad*8) = *(const s8v*)o8;
    if (quad == 0) Lp[(long)z*GQ_ + gq] = Olds[576 + m];
  }
}

// ---------------- combine partials + local 3x3 + learnable tokens -> xo rows --------
__global__ __launch_bounds__(256)
void attn_combine_kernel(const bf16* __restrict__ Op, const float* __restrict__ Lp,
                         const bf16* __restrict__ qs_, const bf16* __restrict__ fused,
                         const float* __restrict__ qe, const float* __restrict__ temp,
                         const float* __restrict__ tokens, const float* __restrict__ tbias,
                         bf16* __restrict__ xo)
{
  int gq = blockIdx.x*256 + threadIdx.x;       // bh*N + n, 25088 total
  int n = gq % N_; int bh = gq / N_; int h = bh & 3; int b = bh >> 2;
  float L = Lp[gq] + Lp[GQ_ + gq];
  const bf16* o0 = Op + (long)gq*32;
  const bf16* o1 = Op + ((long)GQ_ + gq)*32;
  float out[32];
  #pragma unroll
  for (int d=0;d<32;d++) out[d] = cvt(o0[d]) + cvt(o1[d]);
  const bf16* qrow = qs_ + (long)gq*D_;
  float q[32];
  #pragma unroll
  for (int d=0;d<32;d++) q[d] = cvt(qrow[d]);
  int hy = n / W_, wx = n % W_;
  const bf16* kvb = fused + (long)b*N_*FW + 128 + h*D_;   // key cols
  float sl[9];
  #pragma unroll
  for (int k=0;k<9;k++){
    int di = k/3-1, dj = k%3-1;
    int yy = hy+di, xx = wx+dj;
    float s = 0.f;
    if (yy>=0 && yy<H_ && xx>=0 && xx<W_){
      long nn2 = (long)(yy*W_+xx)*FW;
      float dot = 0.f, ss = 0.f;
      #pragma unroll
      for (int d=0;d<32;d++){
        float kk = cvt(kvb[nn2 + d]);
        dot = fmaf(q[d], kk, dot);
        ss  = fmaf(kk, kk, ss);
      }
      s = dot / fmaxf(sqrtf(ss), 1e-12f);
    }
    sl[k] = s;                                  // OOB: exactly 0 (zero-padded key)
  }
  #pragma unroll
  for (int k=0;k<9;k++) L += __expf(sl[k] - 8.f);
  float invL = 1.f/L;
  #pragma unroll
  for (int d=0;d<32;d++) out[d] *= invL;
  float sp = log1pf(expf(temp[h]));
  float invsp = 1.f/sp;
  float qn[32];
  #pragma unroll
  for (int d=0;d<32;d++) qn[d] = q[d]*invsp - qe[h*D_+d];
  #pragma unroll
  for (int k=0;k<9;k++){
    float tok = 0.f;
    #pragma unroll
    for (int d=0;d<32;d++) tok = fmaf(qn[d], tokens[(h*D_+d)*9+k], tok);
    float wl = tok + tbias[h*9+k] + __expf(sl[k] - 8.f)*invL;
    int di = k/3-1, dj = k%3-1;
    int yy = hy+di, xx = wx+dj;
    if (yy>=0 && yy<H_ && xx>=0 && xx<W_){      // OOB v_l zero-padded -> contributes 0
      long nn2 = (long)(yy*W_+xx)*FW;
      #pragma unroll
      for (int d=0;d<32;d++) out[d] = fmaf(wl, cvt(kvb[nn2 + 128 + d]), out[d]);
    }
  }
  bf16* op = xo + ((long)(b*N_ + n))*C_ + h*D_;
  #pragma unroll
  for (int d=0;d<32;d++) stg(&op[d], out[d]);
}

// ---------------- depthwise 3x3 + bias + gelu, gated -> g ROWS (n, 352) ----------------
__global__ __launch_bounds__(256)
void dwconv_kernel(const bf16* __restrict__ f1, const float* __restrict__ dww,
                   const float* __restrict__ dwb, bf16* __restrict__ g)
{
  int t = blockIdx.x*256 + threadIdx.x;
  if (t >= N_*44) return;
  int n = t % N_, cg = t / N_;
  int c0 = cg*8;
  int hy = n / W_, wx = n % W_;
  bf16 o8[8];
  #pragma unroll
  for (int j=0;j<8;j++){
    int c = c0 + j;
    float val = 0.f;
    if (c < HF_){
      const bf16* ap = f1 + (long)c*N_;
      float s = dwb[c];
      #pragma unroll
      for (int di=-1; di<=1; di++)
        #pragma unroll
        for (int dj=-1; dj<=1; dj++){
          int yy = hy+di, xx = wx+dj;
          if (yy>=0 && yy<H_ && xx>=0 && xx<W_)
            s = fmaf(dww[c*9 + (di+1)*3 + (dj+1)], cvt(ap[yy*W_+xx]), s);
        }
      val = gelu_exact(s) * cvt(f1[(long)(HF_+c)*N_ + n]);
    }
    o8[j] = __float2bfloat16(val);
  }
  *(s8v*)(g + (long)n*KF2 + c0) = *(const s8v*)o8;
}

// ---------------- launcher ----------------
extern "C" void kernel_launch(void* const* d_in, const int* in_sizes, int n_in,
                              void* d_out, int out_size, void* d_ws, size_t ws_size,
                              hipStream_t stream)
{
  (void)in_sizes; (void)n_in; (void)out_size; (void)ws_size;
  const float* x_in      = (const float*)d_in[0];
  const float* norm1_w   = (const float*)d_in[1];
  const float* norm1_b   = (const float*)d_in[2];
  const float* q_w       = (const float*)d_in[3];
  const float* q_b       = (const float*)d_in[4];
  const float* kv_w      = (const float*)d_in[5];
  const float* kv_b      = (const float*)d_in[6];
  const float* temp      = (const float*)d_in[7];
  const float* qe        = (const float*)d_in[8];
  const float* tokens    = (const float*)d_in[9];
  const float* tbias     = (const float*)d_in[10];
  const float* sr_w      = (const float*)d_in[11];
  const float* sr_b      = (const float*)d_in[12];
  const float* pln_w     = (const float*)d_in[13];
  const float* pln_b     = (const float*)d_in[14];
  const float* proj_w    = (const float*)d_in[15];
  const float* proj_b    = (const float*)d_in[16];
  const float* norm2_w   = (const float*)d_in[17];
  const float* norm2_b   = (const float*)d_in[18];
  const float* fc1_w     = (const float*)d_in[19];
  const float* fc1_b     = (const float*)d_in[20];
  const float* dw_w      = (const float*)d_in[21];
  const float* dw_b      = (const float*)d_in[22];
  const float* fc2_w     = (const float*)d_in[23];
  const float* fc2_b     = (const float*)d_in[24];

  // ---- workspace plan (bytes), peak 14,881,280 (14.2 MiB, proven round 11) ----
  char* w8 = (char*)d_ws;
  bf16*  fused   = (bf16*)(w8 + 0);
  float* x2      = (float*)(w8 + 0);
  bf16*  y2      = (bf16*)(w8 + 3211264);
  bf16*  f1b     = (bf16*)(w8 + 4816896);
  bf16*  qs      = (bf16*)(w8 + 6422528);
  bf16*  xp      = (bf16*)(w8 + 8028160);
  bf16*  k_p     = (bf16*)(w8 + 8028160);
  bf16*  v_p     = (bf16*)(w8 + 9633792);
  bf16*  g_rows  = (bf16*)(w8 + 9633792);
  bf16*  kvp_raw = (bf16*)(w8 + 11239424);
  bf16*  Opart   = (bf16*)(w8 + 11239424);
  bf16*  wbase   = (bf16*)(w8 + 14450688);
  float* fbias   = (float*)(w8 + 14879232);
  bf16*  y       = f1b;                         // LN1 output rows (dead before f1b use)
  bf16*  xo      = (bf16*)d_out;
  float* Lpart   = (float*)((char*)d_out + 1605632);
  bf16*  proj_wb = wbase + 65536;
  bf16*  fc1_wb  = wbase + 81920;
  bf16*  fc2_wb  = wbase + 169216;

  // 0. weights -> bf16 (fc2 K-padded) + combined qkvsr bias
  convw_kernel<<<(214784+255)/256, 256, 0, stream>>>(
      q_w, kv_w, sr_w, proj_w, fc1_w, fc2_w, q_b, kv_b, sr_b, wbase, fbias);
  // 1. y = LN1(x)
  ln_kernel<float, bf16, true><<<ROWS_/4, 256, 0, stream>>>(x_in, 0, norm1_w, norm1_b, y);
  // 2. fused = y @ [q_w; kv_w; sr_w]^T + bias, gelu on sr cols (384..512)
  gemm_mfma<128, 6, bf16><<<dim3(8,98), 256, 0, stream>>>(y, wbase, fbias, nullptr, fused, ROWS_, FW);
  // 3. qs rows
  post_q_kernel<<<98, 256, 0, stream>>>(fused, qe, temp, qs);
  // 4. xp = LN_pln(fused sr cols)
  ln_kernel<bf16, bf16, false><<<ROWS_/4, 256, 0, stream>>>(fused + 384, FW, pln_w, pln_b, xp);
  // 5. kvp_raw = xp @ kv_w^T + kv_b
  gemm_mfma<128, 1, bf16><<<dim3(4,98), 256, 0, stream>>>(xp, wbase + 16384, kv_b, nullptr, kvp_raw, ROWS_, 256);
  // 6. k_p rows (overwrites xp) + v_p planes
  post_kvp_kernel<<<98, 256, 0, stream>>>(kvp_raw, k_p, v_p);
  // 7. pool-attention partials (2 q-tiles/wave, 2-way key split)
  attn_part_kernel<<<dim3(25,8,2), 256, 0, stream>>>(qs, k_p, v_p, Opart, Lpart);
  // 8. combine + local 3x3 + tokens -> xo (bf16 rows in d_out)
  attn_combine_kernel<<<GQ_/256, 256, 0, stream>>>(Opart, Lpart, qs, fused,
                                                   qe, temp, tokens, tbias, xo);
  // 9. x2 = x_in + (xo @ proj_w^T + proj_b)   (flat-reinterpret residual)
  gemm_mfma<128, 4, float><<<dim3(2,98), 256, 0, stream>>>(xo, proj_wb, proj_b, x_in, x2, ROWS_, 128);
  // 10. y2 = LN2(x2)
  ln_kernel<float, bf16, true><<<ROWS_/4, 256, 0, stream>>>(x2, 0, norm2_w, norm2_b, y2);
  // 11. MLP per batch
  for (int b = 0; b < B_; b++){
    gemm_mfma<128, 3, bf16><<<dim3(49,11), 256, 0, stream>>>(
        fc1_wb, y2 + (long)b*N_*C_, fc1_b, nullptr, f1b, 2*HF_, N_);
    dwconv_kernel<<<(N_*44+255)/256, 256, 0, stream>>>(f1b, dw_w, dw_b, g_rows);
    gemm_mfma<KF2, 5, float><<<dim3(49,2), 256, 0, stream>>>(
        fc2_wb, g_rows, fc2_b, x2 + (long)b*C_*N_,
        ((float*)d_out) + (long)b*C_*N_, C_, N_);
  }
}

// Round 16
// 270.176 us; speedup vs baseline: 4.5631x; 1.1190x over previous
//
#include <hip/hip_runtime.h>
#include <hip/hip_bf16.h>

typedef __hip_bfloat16 bf16;
typedef short s8v __attribute__((ext_vector_type(8)));   // 8 bf16 = 4 VGPR MFMA frag
typedef float f4v __attribute__((ext_vector_type(4)));   // 4 fp32 MFMA acc

#define DEVI __device__ __forceinline__

DEVI float cvt(float x){ return x; }
DEVI float cvt(bf16 x){ return __bfloat162float(x); }

DEVI void stg(float* p, float v){ *p = v; }
DEVI void stg(bf16* p, float v){ *p = __float2bfloat16(v); }

DEVI float gelu_exact(float x){
  return 0.5f*x*(1.0f + erff(x*0.70710678118654752440f));
}

// problem constants
constexpr int B_ = 2, C_ = 128, H_ = 56, W_ = 56, N_ = 3136, NH_ = 4, D_ = 32, HF_ = 341;
constexpr int ROWS_ = B_*N_;             // 6272
constexpr int KF2 = 352;                 // fc2 K padded 341 -> 352 (11*32)
constexpr int GQ_ = NH_*B_*N_;           // 25088 (bh*N + n)
constexpr int FW = 512;                  // fused qkv+sr width (q 0..128 | kv 128..384 | sr 384..512)
constexpr int KSP = 2;                   // attention key splits (round-13 proven config)

// ---------------- LayerNorm (one wave per row of 128 channels) ----------------
template<typename TX, typename TY, bool PLANES>
__global__ __launch_bounds__(256)
void ln_kernel(const TX* __restrict__ x, long xstr, const float* __restrict__ w,
               const float* __restrict__ bia, TY* __restrict__ y)
{
  int gid = blockIdx.x*4 + (threadIdx.x>>6);      // row over B*N
  int lane = threadIdx.x & 63;
  int b = gid / N_, n = gid % N_;
  float v0, v1;
  if (PLANES){
    v0 = cvt(x[((long)b*C_ + lane     )*N_ + n]);
    v1 = cvt(x[((long)b*C_ + lane + 64)*N_ + n]);
  } else {
    v0 = cvt(x[(long)gid*xstr + lane     ]);
    v1 = cvt(x[(long)gid*xstr + lane + 64]);
  }
  float s = v0+v1, ss = v0*v0 + v1*v1;
  #pragma unroll
  for (int o=32;o>0;o>>=1){ s += __shfl_xor(s,o); ss += __shfl_xor(ss,o); }
  float mu  = s*(1.0f/128.0f);
  float var = fmaxf(ss*(1.0f/128.0f) - mu*mu, 0.f);
  float inv = rsqrtf(var + 1e-5f);
  stg(&y[(long)gid*C_ + lane     ], (v0-mu)*inv*w[lane     ] + bia[lane     ]);
  stg(&y[(long)gid*C_ + lane + 64], (v1-mu)*inv*w[lane + 64] + bia[lane + 64]);
}

// ---------------- weight fp32 -> bf16 conversion + combined qkvsr bias ----------------
__global__ __launch_bounds__(256)
void convw_kernel(const float* __restrict__ q_w, const float* __restrict__ kv_w,
                  const float* __restrict__ sr_w, const float* __restrict__ proj_w,
                  const float* __restrict__ fc1_w, const float* __restrict__ fc2_w,
                  const float* __restrict__ q_b, const float* __restrict__ kv_b,
                  const float* __restrict__ sr_b,
                  bf16* __restrict__ out, float* __restrict__ bias_out)
{
  int t = blockIdx.x*256 + threadIdx.x;
  if (t >= 214272){
    int i = t - 214272;
    if (i < 512){
      float bv = (i < 128) ? q_b[i] : (i < 384) ? kv_b[i-128] : sr_b[i-384];
      bias_out[i] = bv;
    }
    return;
  }
  float v;
  if      (t <  16384) v = q_w[t];
  else if (t <  49152) v = kv_w[t-16384];
  else if (t <  65536) v = sr_w[t-49152];
  else if (t <  81920) v = proj_w[t-65536];
  else if (t < 169216) v = fc1_w[t-81920];
  else {
    int i = t - 169216; int m = i / KF2, kp = i % KF2;
    v = (kp < HF_) ? fc2_w[m*HF_ + kp] : 0.f;
  }
  out[t] = __float2bfloat16(v);
}

// ---------------- LDS-free MFMA GEMM (batched via blockIdx.z strides) ----------------
// MODE: 1=+bias[n]; 2=+bias[n]+gelu; 3=+bias[m]; 4=+bias[n]+res fp32; 5=+bias[m]+res fp32;
//       6=+bias[n], gelu iff n>=384 (fused qkv|sr epilogue)
template<int KT, int MODE, typename TC>
__global__ __launch_bounds__(256)
void gemm_mfma(const bf16* __restrict__ A, const bf16* __restrict__ B,
               const float* __restrict__ bias, const float* __restrict__ res,
               TC* __restrict__ Cm, int M, int Nn,
               long sA, long sB, long sC, long sR)
{
  A  += (long)blockIdx.z * sA;
  B  += (long)blockIdx.z * sB;
  Cm += (long)blockIdx.z * sC;
  if (res) res += (long)blockIdx.z * sR;
  int lane = threadIdx.x & 63, w = threadIdx.x >> 6;
  int m = lane & 15, quad = lane >> 4;
  int n0 = blockIdx.x*64, m0 = blockIdx.y*64;
  int arow = m0 + w*16 + m;
  if (arow >= M) arow = M-1;                    // clamp loads; stores guarded
  const bf16* ap = A + (long)arow*KT + quad*8;
  const bf16* bp = B + (long)(n0 + m)*KT + quad*8;
  f4v acc[4];
  #pragma unroll
  for (int s=0;s<4;s++) acc[s] = (f4v){0.f,0.f,0.f,0.f};
  #pragma unroll
  for (int k0 = 0; k0 < KT; k0 += 32){
    s8v af = *(const s8v*)(ap + k0);
    #pragma unroll
    for (int s=0;s<4;s++){
      s8v bf = *(const s8v*)(bp + (long)s*16*KT + k0);
      acc[s] = __builtin_amdgcn_mfma_f32_16x16x32_bf16(af, bf, acc[s], 0, 0, 0);
    }
  }
  #pragma unroll
  for (int s=0;s<4;s++){
    int gn = n0 + s*16 + m;
    #pragma unroll
    for (int r=0;r<4;r++){
      int gm = m0 + w*16 + quad*4 + r;
      if (gm >= M) continue;
      float v = acc[s][r];
      if (MODE==1 || MODE==2 || MODE==4 || MODE==6) v += bias[gn];
      else                                          v += bias[gm];
      if (MODE==2) v = gelu_exact(v);
      if (MODE==6 && gn >= 384) v = gelu_exact(v);
      if (MODE==4 || MODE==5) v += res[(long)gm*Nn + gn];
      stg(&Cm[(long)gm*Nn + gn], v);
    }
  }
}

// ---------------- q post-process: l2n + embed + temperature -> qs ROWS ----------------
__global__ __launch_bounds__(256)
void post_q_kernel(const bf16* __restrict__ fused, const float* __restrict__ qe,
                   const float* __restrict__ temp, bf16* __restrict__ qs)
{
  int t = blockIdx.x*256 + threadIdx.x;        // (b*4+h)*N + n
  int n = t % N_; int bh = t / N_; int h = bh & 3; int b = bh >> 2;
  float sp = log1pf(expf(temp[h]));
  const bf16* qr = fused + ((long)(b*N_ + n))*FW + h*D_;
  float v[32]; float ss = 0.f;
  #pragma unroll
  for (int d=0;d<32;d++){ v[d] = cvt(qr[d]); ss = fmaf(v[d], v[d], ss); }
  float inv = 1.f/fmaxf(sqrtf(ss), 1e-12f);
  bf16* qo = qs + ((long)bh*N_ + n)*D_;
  #pragma unroll
  for (int d=0;d<32;d++)
    stg(&qo[d], (v[d]*inv + qe[h*D_+d])*sp);
}

// ---------------- pooled kv post-process ----------------
__global__ __launch_bounds__(256)
void post_kvp_kernel(const bf16* __restrict__ kvp_raw,
                     bf16* __restrict__ kp, bf16* __restrict__ vp)
{
  int t = blockIdx.x*256 + threadIdx.x;        // bh*N + n
  int n = t % N_; int bh = t / N_; int h = bh & 3; int b = bh >> 2;
  const bf16* kr = kvp_raw + ((long)(b*N_ + n))*(2*C_) + h*D_;
  float v[32]; float ss = 0.f;
  #pragma unroll
  for (int d=0;d<32;d++){ v[d] = cvt(kr[d]); ss = fmaf(v[d], v[d], ss); }
  float inv = 1.f/fmaxf(sqrtf(ss), 1e-12f);
  bf16* ko = kp + ((long)bh*N_ + n)*D_;
  #pragma unroll
  for (int d=0;d<32;d++) stg(&ko[d], v[d]*inv);
  #pragma unroll
  for (int d=0;d<32;d++) vp[((long)bh*D_ + d)*N_ + n] = kr[C_ + d];
}

// ---------------- MFMA pool-attention PARTIAL (2 q-tiles/wave, 2-way key split) -----
// ROUND-13 PROVEN KERNEL (302 us run). grid (25, 8, 2); block 256 = 4 waves.
// Wave w owns q-tiles qA = bx*128 + w*16 and qB = qA+64 (B guarded at tail).
// Per 64-key tile the 8 K/V fragment loads feed 16 MFMAs. No __syncthreads.
__global__ __launch_bounds__(256)
void attn_part_kernel(const bf16* __restrict__ qs_, const bf16* __restrict__ kp_,
                      const bf16* __restrict__ vp_,
                      bf16* __restrict__ Op, float* __restrict__ Lp)
{
  int bh = blockIdx.y;
  int z  = blockIdx.z;
  int lane = threadIdx.x & 63;
  int w    = threadIdx.x >> 6;
  int m    = lane & 15, quad = lane >> 4;
  int qA   = blockIdx.x*128 + w*16;
  int qB   = qA + 64;
  bool hasB = (qB < N_);
  __shared__ float sm[4][1184];                // per wave: PA 16x72 bf16 | PB 16x72 bf16 ; Olds reuses
  bf16*  PA   = (bf16*)sm[w];
  bf16*  PB   = PA + 1152;
  float* Olds = sm[w];

  s8v afA = *(const s8v*)(qs_ + ((long)bh*N_ + qA + m)*D_ + quad*8);
  s8v afB = hasB ? *(const s8v*)(qs_ + ((long)bh*N_ + qB + m)*D_ + quad*8) : afA;
  const bf16* kpb = kp_ + (long)bh*N_*D_;
  const bf16* vpb = vp_ + (long)bh*D_*N_;
  f4v oA0={0.f,0.f,0.f,0.f}, oA1={0.f,0.f,0.f,0.f};
  f4v oB0={0.f,0.f,0.f,0.f}, oB1={0.f,0.f,0.f,0.f};
  float lA[4]={0.f,0.f,0.f,0.f}, lB[4]={0.f,0.f,0.f,0.f};

  int tlo = z*1600, thi = min(tlo + 1600, N_);
  for (int t0 = tlo; t0 < thi; t0 += 64){
    s8v kf[4], vf[4];
    #pragma unroll
    for (int s=0;s<4;s++)
      kf[s] = *(const s8v*)(kpb + (long)(t0 + s*16 + m)*D_ + quad*8);
    vf[0] = *(const s8v*)(vpb + (long)(m     )*N_ + t0      + quad*8);
    vf[1] = *(const s8v*)(vpb + (long)(16 + m)*N_ + t0      + quad*8);
    vf[2] = *(const s8v*)(vpb + (long)(m     )*N_ + t0 + 32 + quad*8);
    vf[3] = *(const s8v*)(vpb + (long)(16 + m)*N_ + t0 + 32 + quad*8);
    // two independent QK chains sharing kf
    #pragma unroll
    for (int s = 0; s < 4; s++){
      f4v cA = {0.f,0.f,0.f,0.f}, cB = {0.f,0.f,0.f,0.f};
      cA = __builtin_amdgcn_mfma_f32_16x16x32_bf16(afA, kf[s], cA, 0, 0, 0);
      cB = __builtin_amdgcn_mfma_f32_16x16x32_bf16(afB, kf[s], cB, 0, 0, 0);
      #pragma unroll
      for (int r=0;r<4;r++){
        float eA = __expf(cA[r] - 8.f);        // D: row=quad*4+r (query), col=m (key)
        float eB = __expf(cB[r] - 8.f);
        lA[r] += eA; lB[r] += eB;
        PA[(quad*4+r)*72 + s*16 + m] = __float2bfloat16(eA);
        PB[(quad*4+r)*72 + s*16 + m] = __float2bfloat16(eB);
      }
    }
    // PV for both chains sharing vf
    #pragma unroll
    for (int c2=0;c2<2;c2++){
      s8v paA = *(const s8v*)(PA + m*72 + c2*32 + quad*8);
      s8v paB = *(const s8v*)(PB + m*72 + c2*32 + quad*8);
      oA0 = __builtin_amdgcn_mfma_f32_16x16x32_bf16(paA, vf[c2*2  ], oA0, 0, 0, 0);
      oA1 = __builtin_amdgcn_mfma_f32_16x16x32_bf16(paA, vf[c2*2+1], oA1, 0, 0, 0);
      oB0 = __builtin_amdgcn_mfma_f32_16x16x32_bf16(paB, vf[c2*2  ], oB0, 0, 0, 0);
      oB1 = __builtin_amdgcn_mfma_f32_16x16x32_bf16(paB, vf[c2*2+1], oB1, 0, 0, 0);
    }
  }
  // merge + store, phase 0 = A, phase 1 = B (wave-private, sequential reuse of Olds)
  #pragma unroll
  for (int ph=0; ph<2; ph++){
    if (ph == 1 && !hasB) break;
    float* lacc = ph ? lB : lA;
    f4v    o0   = ph ? oB0 : oA0;
    f4v    o1   = ph ? oB1 : oA1;
    int    qq   = ph ? qB  : qA;
    float lr[4] = {lacc[0], lacc[1], lacc[2], lacc[3]};
    #pragma unroll
    for (int off=1; off<16; off<<=1)
      #pragma unroll
      for (int r=0;r<4;r++) lr[r] += __shfl_xor(lr[r], off);
    #pragma unroll
    for (int r=0;r<4;r++){
      Olds[(quad*4+r)*36 + m     ] = o0[r];
      Olds[(quad*4+r)*36 + 16 + m] = o1[r];
    }
    if (m == 0){
      #pragma unroll
      for (int r=0;r<4;r++) Olds[576 + quad*4 + r] = lr[r];
    }
    long gq = (long)bh*N_ + qq + m;
    f4v ov0 = *(const f4v*)(Olds + m*36 + quad*8);
    f4v ov1 = *(const f4v*)(Olds + m*36 + quad*8 + 4);
    bf16 o8[8];
    #pragma unroll
    for (int j=0;j<4;j++){ o8[j] = __float2bfloat16(ov0[j]); o8[4+j] = __float2bfloat16(ov1[j]); }
    *(s8v*)(Op + ((long)z*GQ_ + gq)*32 + quad*8) = *(const s8v*)o8;
    if (quad == 0) Lp[(long)z*GQ_ + gq] = Olds[576 + m];
  }
}

// ---------------- combine partials + local 3x3 + learnable tokens -> xo rows --------
__global__ __launch_bounds__(256)
void attn_combine_kernel(const bf16* __restrict__ Op, const float* __restrict__ Lp,
                         const bf16* __restrict__ qs_, const bf16* __restrict__ fused,
                         const float* __restrict__ qe, const float* __restrict__ temp,
                         const float* __restrict__ tokens, const float* __restrict__ tbias,
                         bf16* __restrict__ xo)
{
  int gq = blockIdx.x*256 + threadIdx.x;       // bh*N + n, 25088 total
  int n = gq % N_; int bh = gq / N_; int h = bh & 3; int b = bh >> 2;
  float L = 0.f;
  float out[32];
  #pragma unroll
  for (int d=0;d<32;d++) out[d] = 0.f;
  #pragma unroll
  for (int z=0; z<KSP; z++){
    L += Lp[(long)z*GQ_ + gq];
    const bf16* oz = Op + ((long)z*GQ_ + gq)*32;
    #pragma unroll
    for (int d=0;d<32;d++) out[d] += cvt(oz[d]);
  }
  const bf16* qrow = qs_ + (long)gq*D_;
  float q[32];
  #pragma unroll
  for (int d=0;d<32;d++) q[d] = cvt(qrow[d]);
  int hy = n / W_, wx = n % W_;
  const bf16* kvb = fused + (long)b*N_*FW + 128 + h*D_;   // key cols
  float sl[9];
  #pragma unroll
  for (int k=0;k<9;k++){
    int di = k/3-1, dj = k%3-1;
    int yy = hy+di, xx = wx+dj;
    float s = 0.f;
    if (yy>=0 && yy<H_ && xx>=0 && xx<W_){
      long nn2 = (long)(yy*W_+xx)*FW;
      float dot = 0.f, ss = 0.f;
      #pragma unroll
      for (int d=0;d<32;d++){
        float kk = cvt(kvb[nn2 + d]);
        dot = fmaf(q[d], kk, dot);
        ss  = fmaf(kk, kk, ss);
      }
      s = dot / fmaxf(sqrtf(ss), 1e-12f);
    }
    sl[k] = s;                                  // OOB: exactly 0 (zero-padded key)
  }
  #pragma unroll
  for (int k=0;k<9;k++) L += __expf(sl[k] - 8.f);
  float invL = 1.f/L;
  #pragma unroll
  for (int d=0;d<32;d++) out[d] *= invL;
  float sp = log1pf(expf(temp[h]));
  float invsp = 1.f/sp;
  float qn[32];
  #pragma unroll
  for (int d=0;d<32;d++) qn[d] = q[d]*invsp - qe[h*D_+d];
  #pragma unroll
  for (int k=0;k<9;k++){
    float tok = 0.f;
    #pragma unroll
    for (int d=0;d<32;d++) tok = fmaf(qn[d], tokens[(h*D_+d)*9+k], tok);
    float wl = tok + tbias[h*9+k] + __expf(sl[k] - 8.f)*invL;
    int di = k/3-1, dj = k%3-1;
    int yy = hy+di, xx = wx+dj;
    if (yy>=0 && yy<H_ && xx>=0 && xx<W_){      // OOB v_l zero-padded -> contributes 0
      long nn2 = (long)(yy*W_+xx)*FW;
      #pragma unroll
      for (int d=0;d<32;d++) out[d] = fmaf(wl, cvt(kvb[nn2 + 128 + d]), out[d]);
    }
  }
  bf16* op = xo + ((long)(b*N_ + n))*C_ + h*D_;
  #pragma unroll
  for (int d=0;d<32;d++) stg(&op[d], out[d]);
}

// ---------------- depthwise 3x3 + bias + gelu, gated -> g ROWS (n, 352), both batches
__global__ __launch_bounds__(256)
void dwconv_kernel(const bf16* __restrict__ f1, const float* __restrict__ dww,
                   const float* __restrict__ dwb, bf16* __restrict__ g)
{
  int t = blockIdx.x*256 + threadIdx.x;
  if (t >= B_*N_*44) return;
  int b = t / (N_*44); int r = t - b*(N_*44);
  int n = r % N_, cg = r / N_;
  f1 += (long)b*2*HF_*N_;
  g  += (long)b*N_*KF2;
  int c0 = cg*8;
  int hy = n / W_, wx = n % W_;
  bf16 o8[8];
  #pragma unroll
  for (int j=0;j<8;j++){
    int c = c0 + j;
    float val = 0.f;
    if (c < HF_){
      const bf16* ap = f1 + (long)c*N_;
      float s = dwb[c];
      #pragma unroll
      for (int di=-1; di<=1; di++)
        #pragma unroll
        for (int dj=-1; dj<=1; dj++){
          int yy = hy+di, xx = wx+dj;
          if (yy>=0 && yy<H_ && xx>=0 && xx<W_)
            s = fmaf(dww[c*9 + (di+1)*3 + (dj+1)], cvt(ap[yy*W_+xx]), s);
        }
      val = gelu_exact(s) * cvt(f1[(long)(HF_+c)*N_ + n]);
    }
    o8[j] = __float2bfloat16(val);
  }
  *(s8v*)(g + (long)n*KF2 + c0) = *(const s8v*)o8;
}

// ---------------- launcher ----------------
extern "C" void kernel_launch(void* const* d_in, const int* in_sizes, int n_in,
                              void* d_out, int out_size, void* d_ws, size_t ws_size,
                              hipStream_t stream)
{
  (void)in_sizes; (void)n_in; (void)out_size; (void)ws_size;
  const float* x_in      = (const float*)d_in[0];
  const float* norm1_w   = (const float*)d_in[1];
  const float* norm1_b   = (const float*)d_in[2];
  const float* q_w       = (const float*)d_in[3];
  const float* q_b       = (const float*)d_in[4];
  const float* kv_w      = (const float*)d_in[5];
  const float* kv_b      = (const float*)d_in[6];
  const float* temp      = (const float*)d_in[7];
  const float* qe        = (const float*)d_in[8];
  const float* tokens    = (const float*)d_in[9];
  const float* tbias     = (const float*)d_in[10];
  const float* sr_w      = (const float*)d_in[11];
  const float* sr_b      = (const float*)d_in[12];
  const float* pln_w     = (const float*)d_in[13];
  const float* pln_b     = (const float*)d_in[14];
  const float* proj_w    = (const float*)d_in[15];
  const float* proj_b    = (const float*)d_in[16];
  const float* norm2_w   = (const float*)d_in[17];
  const float* norm2_b   = (const float*)d_in[18];
  const float* fc1_w     = (const float*)d_in[19];
  const float* fc1_b     = (const float*)d_in[20];
  const float* dw_w      = (const float*)d_in[21];
  const float* dw_b      = (const float*)d_in[22];
  const float* fc2_w     = (const float*)d_in[23];
  const float* fc2_b     = (const float*)d_in[24];

  // ---- workspace plan (bytes), peak ~22.5 MB (ws_size ~= 256 MiB per fill counters) ----
  // [0, 6422528):        fused rows -> x2 fp32 [0,3211264) + y2 bf16 [3211264,4816896)
  // [4816896,13371904):  f1b both batches (2 x 682 x N bf16) -- written post-combine;
  //                      LN1 y rows live at its head [4816896,6422528) early on
  // [6422528, 8028160):  qs rows (alive through combine; overwritten later by f1b)
  // [8028160, 9633792):  xp -> k_p rows
  // [9633792, 11239424): v_p planes
  // [11239424,14450688): kvp_raw -> Opart (2 x 25088 x 32 bf16, exact fit)
  // [17661952,22077440): g rows both batches (2 x N x 352 bf16)
  // [22077440,22505984): bf16 weights; [22505984,22508032): fused bias f32
  // d_out: xo bf16 [0,1605632) + Lpart f32 [1605632,1806336); overwritten by fc2.
  char* w8 = (char*)d_ws;
  bf16*  fused   = (bf16*)(w8 + 0);
  float* x2      = (float*)(w8 + 0);
  bf16*  y2      = (bf16*)(w8 + 3211264);
  bf16*  f1b     = (bf16*)(w8 + 4816896);
  bf16*  qs      = (bf16*)(w8 + 6422528);
  bf16*  xp      = (bf16*)(w8 + 8028160);
  bf16*  k_p     = (bf16*)(w8 + 8028160);
  bf16*  v_p     = (bf16*)(w8 + 9633792);
  bf16*  kvp_raw = (bf16*)(w8 + 11239424);
  bf16*  Opart   = (bf16*)(w8 + 11239424);
  bf16*  g_rows  = (bf16*)(w8 + 17661952);
  bf16*  wbase   = (bf16*)(w8 + 22077440);
  float* fbias   = (float*)(w8 + 22505984);
  bf16*  y       = f1b;                         // LN1 output rows (dead before f1b use)
  bf16*  xo      = (bf16*)d_out;
  float* Lpart   = (float*)((char*)d_out + 1605632);
  bf16*  proj_wb = wbase + 65536;
  bf16*  fc1_wb  = wbase + 81920;
  bf16*  fc2_wb  = wbase + 169216;

  // 0. weights -> bf16 (fc2 K-padded) + combined qkvsr bias
  convw_kernel<<<(214784+255)/256, 256, 0, stream>>>(
      q_w, kv_w, sr_w, proj_w, fc1_w, fc2_w, q_b, kv_b, sr_b, wbase, fbias);
  // 1. y = LN1(x)
  ln_kernel<float, bf16, true><<<ROWS_/4, 256, 0, stream>>>(x_in, 0, norm1_w, norm1_b, y);
  // 2. fused = y @ [q_w; kv_w; sr_w]^T + bias, gelu on sr cols (384..512)
  gemm_mfma<128, 6, bf16><<<dim3(8,98), 256, 0, stream>>>(
      y, wbase, fbias, nullptr, fused, ROWS_, FW, 0,0,0,0);
  // 3. qs rows
  post_q_kernel<<<98, 256, 0, stream>>>(fused, qe, temp, qs);
  // 4. xp = LN_pln(fused sr cols)
  ln_kernel<bf16, bf16, false><<<ROWS_/4, 256, 0, stream>>>(fused + 384, FW, pln_w, pln_b, xp);
  // 5. kvp_raw = xp @ kv_w^T + kv_b
  gemm_mfma<128, 1, bf16><<<dim3(4,98), 256, 0, stream>>>(
      xp, wbase + 16384, kv_b, nullptr, kvp_raw, ROWS_, 256, 0,0,0,0);
  // 6. k_p rows (overwrites xp) + v_p planes
  post_kvp_kernel<<<98, 256, 0, stream>>>(kvp_raw, k_p, v_p);
  // 7. pool-attention partials (2 q-tiles/wave, 2-way key split — round-13 proven)
  attn_part_kernel<<<dim3(25,8,KSP), 256, 0, stream>>>(qs, k_p, v_p, Opart, Lpart);
  // 8. combine + local 3x3 + tokens -> xo (bf16 rows in d_out)
  attn_combine_kernel<<<GQ_/256, 256, 0, stream>>>(Opart, Lpart, qs, fused,
                                                   qe, temp, tokens, tbias, xo);
  // 9. x2 = x_in + (xo @ proj_w^T + proj_b)   (flat-reinterpret residual)
  gemm_mfma<128, 4, float><<<dim3(2,98), 256, 0, stream>>>(
      xo, proj_wb, proj_b, x_in, x2, ROWS_, 128, 0,0,0,0);
  // 10. y2 = LN2(x2)
  ln_kernel<float, bf16, true><<<ROWS_/4, 256, 0, stream>>>(x2, 0, norm2_w, norm2_b, y2);
  // 11. MLP, both batches per dispatch (z = batch)
  gemm_mfma<128, 3, bf16><<<dim3(49,11,B_), 256, 0, stream>>>(
      fc1_wb, y2, fc1_b, nullptr, f1b, 2*HF_, N_,
      0, (long)N_*C_, (long)2*HF_*N_, 0);
  dwconv_kernel<<<(B_*N_*44+255)/256, 256, 0, stream>>>(f1b, dw_w, dw_b, g_rows);
  gemm_mfma<KF2, 5, float><<<dim3(49,2,B_), 256, 0, stream>>>(
      fc2_wb, g_rows, fc2_b, x2, (float*)d_out, C_, N_,
      0, (long)N_*KF2, (long)C_*N_, (long)C_*N_);
}